// Round 13
// baseline (761.073 us; speedup 1.0000x reference)
//
#include <hip/hip_runtime.h>
#include <hip/hip_bf16.h>
#include <math.h>

#define Bn 64
#define Pn 512
#define Hn 8
#define Ln 6

typedef __bf16 bf16x8 __attribute__((ext_vector_type(8)));
typedef float f32x4 __attribute__((ext_vector_type(4)));

#define VMCNT(n) asm volatile("s_waitcnt vmcnt(" #n ")" ::: "memory")
#define LGKM0()  asm volatile("s_waitcnt lgkmcnt(0)" ::: "memory")

static __device__ __forceinline__ unsigned short f2bf(float f) {
    return __builtin_bit_cast(unsigned short, __float2bfloat16(f));
}
static __device__ __forceinline__ float bf2f(unsigned short v) {
    unsigned int u = ((unsigned int)v) << 16;
    return __builtin_bit_cast(float, u);
}
static __device__ __forceinline__ float fexp2(float x) {
    float r;
    asm("v_exp_f32 %0, %1" : "=v"(r) : "v"(x));
    return r;
}
static __device__ __forceinline__ unsigned cvtpk(float a, float b) {
    unsigned r;
    asm("v_cvt_pk_bf16_f32 %0, %1, %2" : "=v"(r) : "v"(a), "v"(b));
    return r;
}

#define C1F (1.4426950408889634f / 7.000001f)   // log2(e)/SCALE
#define C2F 43.2808512f                         // 30*log2(e)

// ---------- prep: cast/pad Wq,Wk,Wv -> [L][3][H][64 o][64 i] bf16 (zero-padded)
__global__ __launch_bounds__(256)
void prep_wqkv_kernel(const float* __restrict__ Wq, const float* __restrict__ Wk,
                      const float* __restrict__ Wv, unsigned short* __restrict__ out) {
    int idx = blockIdx.x * 256 + threadIdx.x;
    if (idx >= Ln * 3 * Hn * 4096) return;
    int i = idx & 63, o = (idx >> 6) & 63, h = (idx >> 12) & 7, t = idx >> 15;
    int mat = t % 3, l = t / 3;
    float v = 0.f;
    if (o < 49 && i < 49) {
        const float* src = (mat == 0) ? Wq : (mat == 1) ? Wk : Wv;
        v = src[(((size_t)(l * Hn + h) * 49) + o) * 49 + i];
    }
    out[idx] = f2bf(v);
}

// ---------- prep: Weff[l][h][o2 64][o 64] bf16 = sum_dd Wh[l,h,dd,o]*Wout[l,o2,h*49+dd]
__global__ __launch_bounds__(256)
void prep_weff_kernel(const float* __restrict__ Wh, const float* __restrict__ bh,
                      const float* __restrict__ Wout,
                      unsigned short* __restrict__ Weff, float* __restrict__ beff) {
    const int NW = Ln * Hn * 4096;
    int idx = blockIdx.x * 256 + threadIdx.x;
    if (idx < NW) {
        int o = idx & 63, o2 = (idx >> 6) & 63, h = (idx >> 12) & 7, l = idx >> 15;
        float s = 0.f;
        if (o < 49 && o2 < 49) {
            const float* wh = Wh + ((size_t)(l * Hn + h) * 49) * 49 + o;   // [dd] stride 49
            const float* wo = Wout + ((size_t)l * 49 + o2) * 392 + h * 49; // [dd]
            for (int dd = 0; dd < 49; ++dd) s = fmaf(wh[dd * 49], wo[dd], s);
        }
        Weff[idx] = f2bf(s);
    } else if (idx < NW + Ln * 49) {
        int j = idx - NW;
        int l = j / 49, o2 = j % 49;
        const float* wo = Wout + ((size_t)l * 49 + o2) * 392;
        const float* bhl = bh + (size_t)l * 392;
        float s = 0.f;
        for (int cc = 0; cc < 392; ++cc) s = fmaf(bhl[cc], wo[cc], s);
        beff[j] = s;
    }
}

// ---------- prep: cast embedding -> x_bf [32768][64] padded
__global__ __launch_bounds__(256)
void cast_x_kernel(const float* __restrict__ emb, unsigned short* __restrict__ xbf) {
    int idx = blockIdx.x * 256 + threadIdx.x;
    int row = idx >> 6, col = idx & 63;
    float v = (col < 49) ? emb[(size_t)row * 49 + col] : 0.f;
    xbf[idx] = f2bf(v);
}

// ---------- QKV via MFMA (layer 0 only): 1 wave per 16 rows, direct global frag loads
// Q pre-scaled by log2e/SCALE with Q[:,49] = -30*log2e; K[:,49] = 1; V^T[49][:] = 1.
__global__ __launch_bounds__(64)
void qkv_mfma_kernel(const unsigned short* __restrict__ xbf,
                     const unsigned short* __restrict__ Wqkv,
                     const float* __restrict__ bq_l, const float* __restrict__ bk_l,
                     const float* __restrict__ bv_l,
                     unsigned short* __restrict__ Qb, unsigned short* __restrict__ Kb,
                     unsigned short* __restrict__ Vt,
                     int b_off, int Bc) {
    __shared__ __align__(16) unsigned short stg[16 * 68];   // Q/K re-tile
    __shared__ __align__(16) unsigned short stgv[64 * 16];  // V^T re-tile
    __shared__ __align__(16) float blds[1536];
    const int tid = threadIdx.x;           // 0..63
    const int g = tid >> 4, c = tid & 15;
    const int flat = blockIdx.x;
    const int bl = flat % Bc;
    const int tile = flat / Bc;            // 0..31
    const int r0 = bl * Pn + tile * 16;

    for (int t = tid; t < 1536; t += 64) {
        int mat = t >> 9, rem = t & 511, h = rem >> 6, o = rem & 63;
        const float* bb = (mat == 0) ? bq_l : (mat == 1) ? bk_l : bv_l;
        blds[t] = (o < 49) ? bb[h * 49 + o] : 0.f;
    }
    LGKM0();
    __builtin_amdgcn_sched_barrier(0);

    const unsigned short* xg = xbf + ((size_t)b_off * Pn + r0 + c) * 64;
    bf16x8 a0 = *(const bf16x8*)(xg + g * 8);
    bf16x8 a1 = *(const bf16x8*)(xg + g * 8 + 32);

    for (int panel = 0; panel < 24; ++panel) {
        const int mat = panel >> 3, h = panel & 7;
        const unsigned short* wg = Wqkv + (size_t)panel * 4096;
        const float* bbB = blds + mat * 512 + h * 64;

        f32x4 pacc[4];
        #pragma unroll
        for (int bt = 0; bt < 4; ++bt) pacc[bt] = (f32x4){0.f, 0.f, 0.f, 0.f};

        if (mat < 2) {
            #pragma unroll
            for (int bt = 0; bt < 4; ++bt) {
                const unsigned short* wr = wg + (bt * 16 + c) * 64;
                bf16x8 w0 = *(const bf16x8*)(wr + g * 8);
                bf16x8 w1 = *(const bf16x8*)(wr + g * 8 + 32);
                pacc[bt] = __builtin_amdgcn_mfma_f32_16x16x32_bf16(w0, a0, pacc[bt], 0, 0, 0);
                pacc[bt] = __builtin_amdgcn_mfma_f32_16x16x32_bf16(w1, a1, pacc[bt], 0, 0, 0);
            }
            #pragma unroll
            for (int bt = 0; bt < 4; ++bt) {
                f32x4 bb4 = *(const f32x4*)(bbB + bt * 16 + 4 * g);
                float v0 = pacc[bt][0] + bb4[0];
                float v1 = pacc[bt][1] + bb4[1];
                float v2 = pacc[bt][2] + bb4[2];
                float v3 = pacc[bt][3] + bb4[3];
                if (mat == 0) { v0 *= C1F; v1 *= C1F; v2 *= C1F; v3 *= C1F; }
                if (bt == 3) {
                    float q49 = (mat == 0) ? -C2F : 1.0f;
                    bool g0 = (g == 0);
                    v0 = g0 ? v0 : 0.f;
                    v1 = g0 ? q49 : 0.f;
                    v2 = 0.f; v3 = 0.f;
                }
                uint2 pk = {cvtpk(v0, v1), cvtpk(v2, v3)};
                *(uint2*)((char*)stg + c * 136 + (bt * 16 + 4 * g) * 2) = pk;
            }
            LGKM0();
            __builtin_amdgcn_sched_barrier(0);
            unsigned short* outp = (mat == 0) ? Qb : Kb;
            #pragma unroll
            for (int i = 0; i < 4; ++i) {
                int chunk = i * 64 + tid;
                int prow = chunk >> 4, c4 = chunk & 15;
                uint2 v = *(const uint2*)((const char*)stg + prow * 136 + c4 * 8);
                int rr = r0 + prow;
                int bl2 = rr >> 9, pp = rr & 511;
                *(uint2*)(outp + (((size_t)bl2 * Hn + h) * Pn + pp) * 64 + c4 * 4) = v;
            }
        } else {
            #pragma unroll
            for (int bt = 0; bt < 4; ++bt) {
                const unsigned short* wr = wg + (bt * 16 + c) * 64;
                bf16x8 w0 = *(const bf16x8*)(wr + g * 8);
                bf16x8 w1 = *(const bf16x8*)(wr + g * 8 + 32);
                pacc[bt] = __builtin_amdgcn_mfma_f32_16x16x32_bf16(a0, w0, pacc[bt], 0, 0, 0);
                pacc[bt] = __builtin_amdgcn_mfma_f32_16x16x32_bf16(a1, w1, pacc[bt], 0, 0, 0);
            }
            #pragma unroll
            for (int bt = 0; bt < 4; ++bt) {
                int d = bt * 16 + c;
                float bbd = bbB[d];
                float v0 = pacc[bt][0] + bbd;
                float v1 = pacc[bt][1] + bbd;
                float v2 = pacc[bt][2] + bbd;
                float v3 = pacc[bt][3] + bbd;
                if (bt == 3) {
                    bool is49 = (c == 1);
                    v0 = is49 ? 1.0f : v0;
                    v1 = is49 ? 1.0f : v1;
                    v2 = is49 ? 1.0f : v2;
                    v3 = is49 ? 1.0f : v3;
                }
                uint2 pk = {cvtpk(v0, v1), cvtpk(v2, v3)};
                *(uint2*)((char*)stgv + d * 32 + g * 8) = pk;
            }
            LGKM0();
            __builtin_amdgcn_sched_barrier(0);
            const int bl2 = r0 >> 9, p0 = r0 & 511;
            #pragma unroll
            for (int i = 0; i < 4; ++i) {
                int chunk = i * 64 + tid;
                int drow = chunk >> 2, c4 = chunk & 3;
                uint2 v = *(const uint2*)((const char*)stgv + drow * 32 + c4 * 8);
                *(uint2*)(Vt + (((size_t)bl2 * Hn + h) * 64 + drow) * Pn + p0 + c4 * 4) = v;
            }
        }
    }
}

// ---------- per-head attention: 4 waves x 128 q-rows; async dbuf; in-register P; ones-row denom
__global__ __launch_bounds__(256, 4)
void attn_head_kernel(const unsigned short* __restrict__ Qb,
                      const unsigned short* __restrict__ Kb,
                      const unsigned short* __restrict__ Vt,
                      unsigned short* __restrict__ AO,   // [Bc][H][P][64] bf16
                      int Bc) {
    // 32 KiB: K dbuf 2x8K | V dbuf 2x8K  (epilogue staging reuses K area)
    __shared__ uint4 lds4[2048];
    char* ldsb = (char*)lds4;
    const int tid = threadIdx.x;
    const int w = tid >> 6, lane = tid & 63, g = lane >> 4, c = lane & 15;
    const int flat = blockIdx.x;
    const int x = flat & 7;
    const int qt = (flat >> 3) & 3;
    const int a = flat >> 5;
    const size_t bh = (size_t)(a * 8 + x);
    const int q0 = qt * 128;

    bf16x8 qf[2][2];
    #pragma unroll
    for (int qs = 0; qs < 2; ++qs) {
        const unsigned short* qp = Qb + (bh * Pn + q0 + w * 32 + qs * 16 + c) * 64;
        qf[qs][0] = *(const bf16x8*)(qp + g * 8);
        qf[qs][1] = *(const bf16x8*)(qp + g * 8 + 32);
    }
    f32x4 oacc[2][4];
    #pragma unroll
    for (int qs = 0; qs < 2; ++qs)
        #pragma unroll
        for (int dt = 0; dt < 4; ++dt)
            oacc[qs][dt] = (f32x4){0.f, 0.f, 0.f, 0.f};

    const unsigned short* Kg0 = Kb + bh * (size_t)(Pn * 64);
    const unsigned short* Vg0 = Vt + bh * (size_t)(64 * Pn);

    auto stage = [&](int kt, int buf) {
        const unsigned short* Kg = Kg0 + kt * (64 * 64);
        const unsigned short* Vg = Vg0 + kt * 64;
        #pragma unroll
        for (int j = 0; j < 2; ++j) {
            int chunk = w * 128 + j * 64 + lane;
            int row = chunk >> 3, c8 = chunk & 7;
            int swc = (c8 ^ (row & 7)) << 3;
            __builtin_amdgcn_global_load_lds(
                (const __attribute__((address_space(1))) void*)(Kg + row * 64 + swc),
                (__attribute__((address_space(3))) void*)(ldsb + buf * 8192 + w * 2048 + j * 1024),
                16, 0, 0);
            __builtin_amdgcn_global_load_lds(
                (const __attribute__((address_space(1))) void*)(Vg + (size_t)row * Pn + swc),
                (__attribute__((address_space(3))) void*)(ldsb + 16384 + buf * 8192 + w * 2048 + j * 1024),
                16, 0, 0);
        }
    };

    stage(0, 0);

    #pragma unroll 2
    for (int kt = 0; kt < 8; ++kt) {
        const int cur = kt & 1;
        VMCNT(0);
        __builtin_amdgcn_s_barrier();
        __builtin_amdgcn_sched_barrier(0);
        if (kt < 7) stage(kt + 1, cur ^ 1);
        __builtin_amdgcn_sched_barrier(0);

        char* Klb = ldsb + cur * 8192;
        char* Vlb = ldsb + 16384 + cur * 8192;

        // scores (swapped): s4 = log2e*(QK/SCALE) - 30*log2e directly from MFMA
        unsigned up01[2][4], up23[2][4];
        #pragma unroll
        for (int t = 0; t < 4; ++t) {
            const int krow = t * 16 + c;
            bf16x8 kf0 = *(const bf16x8*)(Klb + krow * 128 + 16 * ((g    ) ^ (krow & 7)));
            bf16x8 kf1 = *(const bf16x8*)(Klb + krow * 128 + 16 * ((g + 4) ^ (krow & 7)));
            #pragma unroll
            for (int qs = 0; qs < 2; ++qs) {
                f32x4 s4 = {0.f, 0.f, 0.f, 0.f};
                __builtin_amdgcn_s_setprio(1);
                s4 = __builtin_amdgcn_mfma_f32_16x16x32_bf16(kf0, qf[qs][0], s4, 0, 0, 0);
                s4 = __builtin_amdgcn_mfma_f32_16x16x32_bf16(kf1, qf[qs][1], s4, 0, 0, 0);
                __builtin_amdgcn_s_setprio(0);
                float p0 = fexp2(s4[0]);
                float p1 = fexp2(s4[1]);
                float p2 = fexp2(s4[2]);
                float p3 = fexp2(s4[3]);
                up01[qs][t] = cvtpk(p0, p1);
                up23[qs][t] = cvtpk(p2, p3);
            }
        }

        // PV: build A-frags in-register via permlane swaps
        #pragma unroll
        for (int kk = 0; kk < 2; ++kk) {
            bf16x8 pa[2];
            #pragma unroll
            for (int qs = 0; qs < 2; ++qs) {
                unsigned d0 = up01[qs][2 * kk], d2 = up01[qs][2 * kk + 1];
                unsigned d1 = up23[qs][2 * kk], d3 = up23[qs][2 * kk + 1];
                asm("v_permlane32_swap_b32 %0, %1" : "+v"(d0), "+v"(d2));
                asm("v_permlane16_swap_b32 %0, %1" : "+v"(d0), "+v"(d2));
                asm("v_permlane32_swap_b32 %0, %1" : "+v"(d1), "+v"(d3));
                asm("v_permlane16_swap_b32 %0, %1" : "+v"(d1), "+v"(d3));
                uint4 uv = {d0, d1, d2, d3};
                pa[qs] = __builtin_bit_cast(bf16x8, uv);
            }
            __builtin_amdgcn_s_setprio(1);
            #pragma unroll
            for (int dt = 0; dt < 4; ++dt) {
                const int vrow = dt * 16 + c;
                bf16x8 vf = *(const bf16x8*)(Vlb + vrow * 128 + 16 * ((g + 4 * kk) ^ (vrow & 7)));
                oacc[0][dt] = __builtin_amdgcn_mfma_f32_16x16x32_bf16(pa[0], vf, oacc[0][dt], 0, 0, 0);
                oacc[1][dt] = __builtin_amdgcn_mfma_f32_16x16x32_bf16(pa[1], vf, oacc[1][dt], 0, 0, 0);
            }
            __builtin_amdgcn_s_setprio(0);
        }
    }
    __builtin_amdgcn_s_barrier();   // all waves done with K/V before reusing K area for staging

    // denom arrived in oacc[qs][3] reg r at lanes c==1 (col 49): broadcast + rcp
    float rinv[2][4];
    #pragma unroll
    for (int qs = 0; qs < 2; ++qs)
        #pragma unroll
        for (int r = 0; r < 4; ++r) {
            float s = __shfl(oacc[qs][3][r], (lane & 48) | 1);
            rinv[qs][r] = 1.0f / s;
        }
    char* stgw = ldsb + w * 4096;
    #pragma unroll
    for (int qs = 0; qs < 2; ++qs)
        #pragma unroll
        for (int dt = 0; dt < 4; ++dt)
            #pragma unroll
            for (int r = 0; r < 4; ++r) {
                int prow = qs * 16 + 4 * g + r;
                int col = dt * 16 + c;
                *(unsigned short*)(stgw + prow * 128 + ((2 * col) ^ ((prow & 7) << 4))) =
                    f2bf(oacc[qs][dt][r] * rinv[qs][r]);
            }
    LGKM0();
    __builtin_amdgcn_sched_barrier(0);
    #pragma unroll
    for (int i = 0; i < 4; ++i) {
        int chunk = i * 64 + lane;
        int row = chunk >> 3, c8 = chunk & 7;
        uint4 v = *(const uint4*)(stgw + row * 128 + 16 * (c8 ^ (row & 7)));
        size_t grow = bh * Pn + q0 + w * 32 + row;
        *(uint4*)(AO + grow * 64 + c8 * 8) = v;
    }
}

// ---------- fused out-projection + next-layer QKV: 1 wave per 16 rows, no barriers
__global__ __launch_bounds__(64)
void outqkv_kernel(const unsigned short* __restrict__ AO,     // [Bc][H][P][64]
                   const unsigned short* __restrict__ Weffl,  // [8][64][64]
                   const float* __restrict__ beffl,           // [49]
                   const unsigned short* __restrict__ Wqkv,   // next layer [3][8][64][64]
                   const float* __restrict__ bq_l, const float* __restrict__ bk_l,
                   const float* __restrict__ bv_l,
                   unsigned short* __restrict__ Qb, unsigned short* __restrict__ Kb,
                   unsigned short* __restrict__ Vt,
                   unsigned short* __restrict__ xout,         // used only when last
                   int last, int b_off, int Bc) {
    __shared__ __align__(16) unsigned short stg[16 * 68];   // Q/K/x re-tile
    __shared__ __align__(16) unsigned short stgv[64 * 16];  // V^T re-tile
    __shared__ __align__(16) char xlds[2048];               // x-tile (swizzled)
    __shared__ __align__(16) float blds[1536];
    __shared__ __align__(16) float bldc[64];
    const int tid = threadIdx.x;           // 0..63
    const int g = tid >> 4, c = tid & 15;
    const int flat = blockIdx.x;
    const int bl = flat % Bc;
    const int tile = flat / Bc;            // 0..31
    const int p0 = tile * 16;
    const int r0 = bl * Pn + p0;

    if (!last) {
        for (int t = tid; t < 1536; t += 64) {
            int mat = t >> 9, rem = t & 511, h = rem >> 6, o = rem & 63;
            const float* bb = (mat == 0) ? bq_l : (mat == 1) ? bk_l : bv_l;
            blds[t] = (o < 49) ? bb[h * 49 + o] : 0.f;
        }
    }
    bldc[tid] = (tid < 49) ? beffl[tid] : 0.f;
    LGKM0();
    __builtin_amdgcn_sched_barrier(0);

    // ---- Phase A: out-projection over 8 heads (swapped: D[o2=bt*16+4g+r][p=c])
    f32x4 acc[4];
    #pragma unroll
    for (int bt = 0; bt < 4; ++bt) acc[bt] = (f32x4){0.f, 0.f, 0.f, 0.f};

    #pragma unroll 2
    for (int h = 0; h < Hn; ++h) {
        const unsigned short* Ag = AO + (((size_t)bl * Hn + h) * Pn + p0 + c) * 64;
        bf16x8 a0 = *(const bf16x8*)(Ag + g * 8);
        bf16x8 a1 = *(const bf16x8*)(Ag + g * 8 + 32);
        const unsigned short* Wg = Weffl + (size_t)h * 4096;
        #pragma unroll
        for (int bt = 0; bt < 4; ++bt) {
            const unsigned short* wr = Wg + (bt * 16 + c) * 64;
            bf16x8 w0 = *(const bf16x8*)(wr + g * 8);
            bf16x8 w1 = *(const bf16x8*)(wr + g * 8 + 32);
            acc[bt] = __builtin_amdgcn_mfma_f32_16x16x32_bf16(w0, a0, acc[bt], 0, 0, 0);
            acc[bt] = __builtin_amdgcn_mfma_f32_16x16x32_bf16(w1, a1, acc[bt], 0, 0, 0);
        }
    }

    if (last) {
        #pragma unroll
        for (int bt = 0; bt < 4; ++bt) {
            f32x4 bb4 = *(const f32x4*)(bldc + bt * 16 + 4 * g);
            uint2 pk = {cvtpk(acc[bt][0] + bb4[0], acc[bt][1] + bb4[1]),
                        cvtpk(acc[bt][2] + bb4[2], acc[bt][3] + bb4[3])};
            *(uint2*)((char*)stg + c * 136 + (bt * 16 + 4 * g) * 2) = pk;
        }
        LGKM0();
        __builtin_amdgcn_sched_barrier(0);
        #pragma unroll
        for (int i = 0; i < 4; ++i) {
            int chunk = i * 64 + tid;
            int prow = chunk >> 4, c4 = chunk & 15;
            uint2 v = *(const uint2*)((const char*)stg + prow * 136 + c4 * 8);
            size_t grow = (size_t)(b_off + bl) * Pn + p0 + prow;
            *(uint2*)(xout + grow * 64 + c4 * 4) = v;
        }
        return;
    }

    // ---- Phase B: x-tile (bf16) into xlds, swizzled b64 writes
    #pragma unroll
    for (int bt = 0; bt < 4; ++bt) {
        f32x4 bb4 = *(const f32x4*)(bldc + bt * 16 + 4 * g);
        uint2 pk = {cvtpk(acc[bt][0] + bb4[0], acc[bt][1] + bb4[1]),
                    cvtpk(acc[bt][2] + bb4[2], acc[bt][3] + bb4[3])};
        *(uint2*)(xlds + c * 128 + ((2 * (bt * 16 + 4 * g)) ^ ((c & 7) << 4))) = pk;
    }
    LGKM0();
    __builtin_amdgcn_sched_barrier(0);
    bf16x8 a0 = *(const bf16x8*)(xlds + c * 128 + 16 * ((g    ) ^ (c & 7)));
    bf16x8 a1 = *(const bf16x8*)(xlds + c * 128 + 16 * ((g + 4) ^ (c & 7)));

    // ---- Phase C: next-layer QKV, 24 panels, direct global W frag loads
    for (int panel = 0; panel < 24; ++panel) {
        const int mat = panel >> 3, h = panel & 7;
        const unsigned short* wg = Wqkv + (size_t)panel * 4096;
        const float* bbB = blds + mat * 512 + h * 64;

        f32x4 pacc[4];
        #pragma unroll
        for (int bt = 0; bt < 4; ++bt) pacc[bt] = (f32x4){0.f, 0.f, 0.f, 0.f};

        if (mat < 2) {
            #pragma unroll
            for (int bt = 0; bt < 4; ++bt) {
                const unsigned short* wr = wg + (bt * 16 + c) * 64;
                bf16x8 w0 = *(const bf16x8*)(wr + g * 8);
                bf16x8 w1 = *(const bf16x8*)(wr + g * 8 + 32);
                pacc[bt] = __builtin_amdgcn_mfma_f32_16x16x32_bf16(w0, a0, pacc[bt], 0, 0, 0);
                pacc[bt] = __builtin_amdgcn_mfma_f32_16x16x32_bf16(w1, a1, pacc[bt], 0, 0, 0);
            }
            #pragma unroll
            for (int bt = 0; bt < 4; ++bt) {
                f32x4 bb4 = *(const f32x4*)(bbB + bt * 16 + 4 * g);
                float v0 = pacc[bt][0] + bb4[0];
                float v1 = pacc[bt][1] + bb4[1];
                float v2 = pacc[bt][2] + bb4[2];
                float v3 = pacc[bt][3] + bb4[3];
                if (mat == 0) { v0 *= C1F; v1 *= C1F; v2 *= C1F; v3 *= C1F; }
                if (bt == 3) {
                    float q49 = (mat == 0) ? -C2F : 1.0f;
                    bool g0 = (g == 0);
                    v0 = g0 ? v0 : 0.f;
                    v1 = g0 ? q49 : 0.f;
                    v2 = 0.f; v3 = 0.f;
                }
                uint2 pk = {cvtpk(v0, v1), cvtpk(v2, v3)};
                *(uint2*)((char*)stg + c * 136 + (bt * 16 + 4 * g) * 2) = pk;
            }
            LGKM0();
            __builtin_amdgcn_sched_barrier(0);
            unsigned short* outp = (mat == 0) ? Qb : Kb;
            #pragma unroll
            for (int i = 0; i < 4; ++i) {
                int chunk = i * 64 + tid;
                int prow = chunk >> 4, c4 = chunk & 15;
                uint2 v = *(const uint2*)((const char*)stg + prow * 136 + c4 * 8);
                int rr = r0 + prow;
                int bl2 = rr >> 9, pp = rr & 511;
                *(uint2*)(outp + (((size_t)bl2 * Hn + h) * Pn + pp) * 64 + c4 * 4) = v;
            }
        } else {
            #pragma unroll
            for (int bt = 0; bt < 4; ++bt) {
                const unsigned short* wr = wg + (bt * 16 + c) * 64;
                bf16x8 w0 = *(const bf16x8*)(wr + g * 8);
                bf16x8 w1 = *(const bf16x8*)(wr + g * 8 + 32);
                pacc[bt] = __builtin_amdgcn_mfma_f32_16x16x32_bf16(a0, w0, pacc[bt], 0, 0, 0);
                pacc[bt] = __builtin_amdgcn_mfma_f32_16x16x32_bf16(a1, w1, pacc[bt], 0, 0, 0);
            }
            #pragma unroll
            for (int bt = 0; bt < 4; ++bt) {
                int d = bt * 16 + c;
                float bbd = bbB[d];
                float v0 = pacc[bt][0] + bbd;
                float v1 = pacc[bt][1] + bbd;
                float v2 = pacc[bt][2] + bbd;
                float v3 = pacc[bt][3] + bbd;
                if (bt == 3) {
                    bool is49 = (c == 1);
                    v0 = is49 ? 1.0f : v0;
                    v1 = is49 ? 1.0f : v1;
                    v2 = is49 ? 1.0f : v2;
                    v3 = is49 ? 1.0f : v3;
                }
                uint2 pk = {cvtpk(v0, v1), cvtpk(v2, v3)};
                *(uint2*)((char*)stgv + d * 32 + g * 8) = pk;
            }
            LGKM0();
            __builtin_amdgcn_sched_barrier(0);
            #pragma unroll
            for (int i = 0; i < 4; ++i) {
                int chunk = i * 64 + tid;
                int drow = chunk >> 2, c4 = chunk & 3;
                uint2 v = *(const uint2*)((const char*)stgv + drow * 32 + c4 * 8);
                *(uint2*)(Vt + (((size_t)bl * Hn + h) * 64 + drow) * Pn + p0 + c4 * 4) = v;
            }
        }
    }
}

// ---------- mean-pool over P (bf16 input)
__global__ __launch_bounds__(256)
void pool_kernel(const unsigned short* __restrict__ x, float* __restrict__ pooled) {
    __shared__ float red[256];
    const int b = blockIdx.x;
    const int tid = threadIdx.x;
    const int ps = tid >> 6, d = tid & 63;
    float s = 0.f;
    for (int p = ps; p < Pn; p += 4) s += bf2f(x[((size_t)b * Pn + p) * 64 + d]);
    red[tid] = s;
    __syncthreads();
    if (tid < 64) {
        float t = red[tid] + red[tid + 64] + red[tid + 128] + red[tid + 192];
        if (tid < 49) pooled[b * 49 + tid] = t * (1.0f / Pn);
    }
}

// ---------- MLP + log-softmax + NLL
__global__ __launch_bounds__(64)
void head_kernel(const float* __restrict__ pooled, const int* __restrict__ labels,
                 const float* __restrict__ W1, const float* __restrict__ b1,
                 const float* __restrict__ W2, const float* __restrict__ b2,
                 float* __restrict__ out) {
    __shared__ float lloss[64];
    const int b = threadIdx.x;
    float pr[49];
    #pragma unroll
    for (int i = 0; i < 49; ++i) pr[i] = pooled[b * 49 + i];
    float hh[25];
    for (int j = 0; j < 25; ++j) {
        float s = b1[j];
        for (int i = 0; i < 49; ++i) s = fmaf(pr[i], W1[j * 49 + i], s);
        hh[j] = fmaxf(s, 0.f);
    }
    float lg[10];
    float m = -1e30f;
    for (int k = 0; k < 10; ++k) {
        float s = b2[k];
        for (int j = 0; j < 25; ++j) s = fmaf(hh[j], W2[k * 25 + j], s);
        lg[k] = s;
        m = fmaxf(m, s);
    }
    float se = 0.f;
    for (int k = 0; k < 10; ++k) se += __expf(lg[k] - m);
    float lse = m + __logf(se);
    int lbl = labels[b];
    lloss[b] = lse - lg[lbl];
    __syncthreads();
    if (b == 0) {
        float s = 0.f;
        for (int i = 0; i < 64; ++i) s += lloss[i];
        out[0] = s * (1.0f / 64.0f);
    }
}

extern "C" void kernel_launch(void* const* d_in, const int* in_sizes, int n_in,
                              void* d_out, int out_size, void* d_ws, size_t ws_size,
                              hipStream_t stream) {
    const float* emb    = (const float*)d_in[0];
    const int*   labels = (const int*)d_in[1];
    const float* Wq = (const float*)d_in[2];
    const float* bq = (const float*)d_in[3];
    const float* Wk = (const float*)d_in[4];
    const float* bk = (const float*)d_in[5];
    const float* Wv = (const float*)d_in[6];
    const float* bv = (const float*)d_in[7];
    const float* Wh = (const float*)d_in[8];
    const float* bhp = (const float*)d_in[9];
    const float* Wout = (const float*)d_in[10];
    const float* W1 = (const float*)d_in[11];
    const float* b1 = (const float*)d_in[12];
    const float* W2 = (const float*)d_in[13];
    const float* b2 = (const float*)d_in[14];
    float* out = (float*)d_out;

    char* base = (char*)d_ws;
    size_t off = 0;
    auto alloc = [&](size_t bytes) {
        off = (off + 255) & ~(size_t)255;
        char* p = base + off;
        off += bytes;
        return p;
    };

    unsigned short* WqkvB = (unsigned short*)alloc((size_t)Ln * 3 * Hn * 4096 * 2);
    unsigned short* WeffB = (unsigned short*)alloc((size_t)Ln * Hn * 4096 * 2);
    float*          beffB = (float*)alloc((size_t)Ln * 49 * 4);
    unsigned short* xA    = (unsigned short*)alloc((size_t)Bn * Pn * 64 * 2);
    unsigned short* xB    = (unsigned short*)alloc((size_t)Bn * Pn * 64 * 2);
    float*          pooled = (float*)alloc((size_t)Bn * 49 * 4);

    const size_t per_b = 4 * ((size_t)Hn * Pn * 64 * 2);   // Q + K + Vt + AO bf16
    size_t fixed = (off + 255) & ~(size_t)255;
    int Bc = Bn;
    while (Bc > 8 && fixed + (size_t)Bc * per_b + 4096 > ws_size) Bc >>= 1;

    unsigned short* Qb  = (unsigned short*)alloc((size_t)Bc * Hn * Pn * 64 * 2);
    unsigned short* Kb  = (unsigned short*)alloc((size_t)Bc * Hn * Pn * 64 * 2);
    unsigned short* Vtb = (unsigned short*)alloc((size_t)Bc * Hn * Pn * 64 * 2);
    unsigned short* AOb = (unsigned short*)alloc((size_t)Bc * Hn * Pn * 64 * 2);

    prep_wqkv_kernel<<<(Ln * 3 * Hn * 4096 + 255) / 256, 256, 0, stream>>>(Wq, Wk, Wv, WqkvB);
    prep_weff_kernel<<<(Ln * Hn * 4096 + Ln * 49 + 255) / 256, 256, 0, stream>>>(Wh, bhp, Wout, WeffB, beffB);
    cast_x_kernel<<<(Bn * Pn * 64) / 256, 256, 0, stream>>>(emb, xA);

    for (int b0 = 0; b0 < Bn; b0 += Bc) {
        qkv_mfma_kernel<<<Bc * 32, 64, 0, stream>>>(
            xA, WqkvB, bq, bk, bv, Qb, Kb, Vtb, b0, Bc);
        for (int l = 0; l < Ln; ++l) {
            attn_head_kernel<<<Bc * 32, 256, 0, stream>>>(Qb, Kb, Vtb, AOb, Bc);
            int last = (l == Ln - 1) ? 1 : 0;
            int ln = last ? 0 : (l + 1);
            outqkv_kernel<<<Bc * 32, 64, 0, stream>>>(
                AOb,
                WeffB + (size_t)l * Hn * 4096,
                beffB + (size_t)l * 49,
                WqkvB + (size_t)ln * 3 * Hn * 4096,
                bq + (size_t)ln * Hn * 49,
                bk + (size_t)ln * Hn * 49,
                bv + (size_t)ln * Hn * 49,
                Qb, Kb, Vtb, xB, last, b0, Bc);
        }
    }

    pool_kernel<<<Bn, 256, 0, stream>>>(xB, pooled);
    head_kernel<<<1, 64, 0, stream>>>(pooled, labels, W1, b1, W2, b2, out);
}

// Round 14
// 499.892 us; speedup vs baseline: 1.5225x; 1.5225x over previous
//
#include <hip/hip_runtime.h>
#include <hip/hip_bf16.h>
#include <math.h>

#define Bn 64
#define Pn 512
#define Hn 8
#define Ln 6

typedef __bf16 bf16x8 __attribute__((ext_vector_type(8)));
typedef float f32x4 __attribute__((ext_vector_type(4)));

#define VMCNT(n) asm volatile("s_waitcnt vmcnt(" #n ")" ::: "memory")
#define LGKM0()  asm volatile("s_waitcnt lgkmcnt(0)" ::: "memory")

static __device__ __forceinline__ unsigned short f2bf(float f) {
    return __builtin_bit_cast(unsigned short, __float2bfloat16(f));
}
static __device__ __forceinline__ float bf2f(unsigned short v) {
    unsigned int u = ((unsigned int)v) << 16;
    return __builtin_bit_cast(float, u);
}
static __device__ __forceinline__ float fexp2(float x) {
    float r;
    asm("v_exp_f32 %0, %1" : "=v"(r) : "v"(x));
    return r;
}
static __device__ __forceinline__ unsigned cvtpk(float a, float b) {
    unsigned r;
    asm("v_cvt_pk_bf16_f32 %0, %1, %2" : "=v"(r) : "v"(a), "v"(b));
    return r;
}

#define C1F (1.4426950408889634f / 7.000001f)   // log2(e)/SCALE
#define C2F 43.2808512f                         // 30*log2(e)

// ---------- prep: cast/pad Wq,Wk,Wv -> [L][3][H][64 o][64 i] bf16 (zero-padded)
__global__ __launch_bounds__(256)
void prep_wqkv_kernel(const float* __restrict__ Wq, const float* __restrict__ Wk,
                      const float* __restrict__ Wv, unsigned short* __restrict__ out) {
    int idx = blockIdx.x * 256 + threadIdx.x;
    if (idx >= Ln * 3 * Hn * 4096) return;
    int i = idx & 63, o = (idx >> 6) & 63, h = (idx >> 12) & 7, t = idx >> 15;
    int mat = t % 3, l = t / 3;
    float v = 0.f;
    if (o < 49 && i < 49) {
        const float* src = (mat == 0) ? Wq : (mat == 1) ? Wk : Wv;
        v = src[(((size_t)(l * Hn + h) * 49) + o) * 49 + i];
    }
    out[idx] = f2bf(v);
}

// ---------- prep: Weff[l][h][o2 64][o 64] bf16 = sum_dd Wh[l,h,dd,o]*Wout[l,o2,h*49+dd]
__global__ __launch_bounds__(256)
void prep_weff_kernel(const float* __restrict__ Wh, const float* __restrict__ bh,
                      const float* __restrict__ Wout,
                      unsigned short* __restrict__ Weff, float* __restrict__ beff) {
    const int NW = Ln * Hn * 4096;
    int idx = blockIdx.x * 256 + threadIdx.x;
    if (idx < NW) {
        int o = idx & 63, o2 = (idx >> 6) & 63, h = (idx >> 12) & 7, l = idx >> 15;
        float s = 0.f;
        if (o < 49 && o2 < 49) {
            const float* wh = Wh + ((size_t)(l * Hn + h) * 49) * 49 + o;   // [dd] stride 49
            const float* wo = Wout + ((size_t)l * 49 + o2) * 392 + h * 49; // [dd]
            for (int dd = 0; dd < 49; ++dd) s = fmaf(wh[dd * 49], wo[dd], s);
        }
        Weff[idx] = f2bf(s);
    } else if (idx < NW + Ln * 49) {
        int j = idx - NW;
        int l = j / 49, o2 = j % 49;
        const float* wo = Wout + ((size_t)l * 49 + o2) * 392;
        const float* bhl = bh + (size_t)l * 392;
        float s = 0.f;
        for (int cc = 0; cc < 392; ++cc) s = fmaf(bhl[cc], wo[cc], s);
        beff[j] = s;
    }
}

// ---------- prep: cast embedding -> x_bf [32768][64] padded
__global__ __launch_bounds__(256)
void cast_x_kernel(const float* __restrict__ emb, unsigned short* __restrict__ xbf) {
    int idx = blockIdx.x * 256 + threadIdx.x;
    int row = idx >> 6, col = idx & 63;
    float v = (col < 49) ? emb[(size_t)row * 49 + col] : 0.f;
    xbf[idx] = f2bf(v);
}

// ---------- QKV via MFMA (layer 0 only)
// Q pre-scaled by log2e/SCALE with Q[:,49] = -30*log2e; K[:,49] = 1; V^T[49][:] = 1.
__global__ __launch_bounds__(256)
void qkv_mfma_kernel(const unsigned short* __restrict__ xbf,
                     const unsigned short* __restrict__ Wqkv,
                     const float* __restrict__ bq_l, const float* __restrict__ bk_l,
                     const float* __restrict__ bv_l,
                     unsigned short* __restrict__ Qb, unsigned short* __restrict__ Kb,
                     unsigned short* __restrict__ Vt,
                     int b_off, int Bc) {
    __shared__ uint4 xlb4[512];
    __shared__ uint4 wlb4[512];
    __shared__ __align__(16) unsigned short stg[64 * 68];
    __shared__ __align__(16) float blds[1536];
    char* xlb = (char*)xlb4;
    char* wlb = (char*)wlb4;
    const int tid = threadIdx.x;
    const int w = tid >> 6, lane = tid & 63, g = lane >> 4, c = lane & 15;
    const int flat = blockIdx.x;
    const int bl = flat % Bc;
    const int tile = flat / Bc;
    const int r0 = bl * Pn + tile * 64;

    for (int t = tid; t < 1536; t += 256) {
        int mat = t >> 9, rem = t & 511, h = rem >> 6, o = rem & 63;
        const float* bb = (mat == 0) ? bq_l : (mat == 1) ? bk_l : bv_l;
        blds[t] = (o < 49) ? bb[h * 49 + o] : 0.f;
    }
    {
        const unsigned short* xg = xbf + ((size_t)b_off * Pn + r0) * 64;
        #pragma unroll
        for (int i = 0; i < 2; ++i) {
            int chunk = tid + i * 256;
            int row = chunk >> 3, c8 = chunk & 7;
            *(uint4*)(xlb + row * 128 + 16 * (c8 ^ (row & 7))) =
                *(const uint4*)(xg + row * 64 + c8 * 8);
        }
    }
    __syncthreads();

    const int rowa = w * 16 + c;
    bf16x8 a0 = *(const bf16x8*)(xlb + rowa * 128 + 16 * ((g    ) ^ (c & 7)));
    bf16x8 a1 = *(const bf16x8*)(xlb + rowa * 128 + 16 * ((g + 4) ^ (c & 7)));

    for (int panel = 0; panel < 24; ++panel) {
        const int mat = panel >> 3, h = panel & 7;
        const unsigned short* wg = Wqkv + (size_t)panel * 4096;
        #pragma unroll
        for (int i = 0; i < 2; ++i) {
            int chunk = tid + i * 256;
            int row = chunk >> 3, c8 = chunk & 7;
            *(uint4*)(wlb + row * 128 + 16 * (c8 ^ (row & 7))) =
                *(const uint4*)(wg + row * 64 + c8 * 8);
        }
        __syncthreads();

        f32x4 acc[4];
        #pragma unroll
        for (int bt = 0; bt < 4; ++bt) acc[bt] = (f32x4){0.f, 0.f, 0.f, 0.f};
        const float* bbB = blds + mat * 512 + h * 64;

        if (mat < 2) {
            // swapped: D[o=bt*16+4g+r][p=w*16+c] -> 4 consecutive o per lane
            #pragma unroll
            for (int bt = 0; bt < 4; ++bt) {
                int rowb = bt * 16 + c;
                bf16x8 w0 = *(const bf16x8*)(wlb + rowb * 128 + 16 * ((g    ) ^ (rowb & 7)));
                bf16x8 w1 = *(const bf16x8*)(wlb + rowb * 128 + 16 * ((g + 4) ^ (rowb & 7)));
                acc[bt] = __builtin_amdgcn_mfma_f32_16x16x32_bf16(w0, a0, acc[bt], 0, 0, 0);
                acc[bt] = __builtin_amdgcn_mfma_f32_16x16x32_bf16(w1, a1, acc[bt], 0, 0, 0);
            }
            const int p = w * 16 + c;
            #pragma unroll
            for (int bt = 0; bt < 4; ++bt) {
                f32x4 bb4 = *(const f32x4*)(bbB + bt * 16 + 4 * g);
                float v0 = acc[bt][0] + bb4[0];
                float v1 = acc[bt][1] + bb4[1];
                float v2 = acc[bt][2] + bb4[2];
                float v3 = acc[bt][3] + bb4[3];
                if (mat == 0) { v0 *= C1F; v1 *= C1F; v2 *= C1F; v3 *= C1F; }
                if (bt == 3) {
                    float q49 = (mat == 0) ? -C2F : 1.0f;
                    bool g0 = (g == 0);          // o = 48+4g+r
                    v0 = g0 ? v0 : 0.f;
                    v1 = g0 ? q49 : 0.f;
                    v2 = 0.f; v3 = 0.f;
                }
                uint2 pk = {cvtpk(v0, v1), cvtpk(v2, v3)};
                *(uint2*)((char*)stg + p * 136 + (bt * 16 + 4 * g) * 2) = pk;
            }
        } else {
            // original: D[p=w*16+4g+r][o=bt*16+c] -> 4 consecutive p per lane (V^T)
            #pragma unroll
            for (int bt = 0; bt < 4; ++bt) {
                int rowb = bt * 16 + c;
                bf16x8 w0 = *(const bf16x8*)(wlb + rowb * 128 + 16 * ((g    ) ^ (rowb & 7)));
                bf16x8 w1 = *(const bf16x8*)(wlb + rowb * 128 + 16 * ((g + 4) ^ (rowb & 7)));
                acc[bt] = __builtin_amdgcn_mfma_f32_16x16x32_bf16(a0, w0, acc[bt], 0, 0, 0);
                acc[bt] = __builtin_amdgcn_mfma_f32_16x16x32_bf16(a1, w1, acc[bt], 0, 0, 0);
            }
            #pragma unroll
            for (int bt = 0; bt < 4; ++bt) {
                int d = bt * 16 + c;
                float bbd = bbB[d];
                float v0 = acc[bt][0] + bbd;
                float v1 = acc[bt][1] + bbd;
                float v2 = acc[bt][2] + bbd;
                float v3 = acc[bt][3] + bbd;
                if (bt == 3) {
                    bool is49 = (c == 1);        // d = 48+c
                    v0 = is49 ? 1.0f : v0;
                    v1 = is49 ? 1.0f : v1;
                    v2 = is49 ? 1.0f : v2;
                    v3 = is49 ? 1.0f : v3;
                }
                uint2 pk = {cvtpk(v0, v1), cvtpk(v2, v3)};
                *(uint2*)((char*)stg + d * 136 + (w * 16 + 4 * g) * 2) = pk;
            }
        }
        __syncthreads();

        if (mat < 2) {
            unsigned short* outp = (mat == 0) ? Qb : Kb;
            #pragma unroll
            for (int i = 0; i < 4; ++i) {
                int chunk = tid + i * 256;
                int prow = chunk >> 4, c4 = chunk & 15;
                uint2 v = *(const uint2*)((const char*)stg + prow * 136 + c4 * 8);
                int rr = r0 + prow;
                int bl2 = rr >> 9, p = rr & 511;
                *(uint2*)(outp + (((size_t)bl2 * Hn + h) * Pn + p) * 64 + c4 * 4) = v;
            }
        } else {
            const int bl2 = r0 >> 9, p0 = r0 & 511;
            #pragma unroll
            for (int i = 0; i < 4; ++i) {
                int chunk = tid + i * 256;
                int drow = chunk >> 4, c4 = chunk & 15;
                uint2 v = *(const uint2*)((const char*)stg + drow * 136 + c4 * 8);
                *(uint2*)(Vt + (((size_t)bl2 * Hn + h) * 64 + drow) * Pn + p0 + c4 * 4) = v;
            }
        }
        __syncthreads();
    }
}

// ---------- per-head attention: 4 waves x 128 q-rows; async dbuf; in-register P; ones-row denom
__global__ __launch_bounds__(256, 4)
void attn_head_kernel(const unsigned short* __restrict__ Qb,
                      const unsigned short* __restrict__ Kb,
                      const unsigned short* __restrict__ Vt,
                      unsigned short* __restrict__ AO,   // [Bc][H][P][64] bf16
                      int Bc) {
    // 32 KiB: K dbuf 2x8K | V dbuf 2x8K  (epilogue staging reuses K area)
    __shared__ uint4 lds4[2048];
    char* ldsb = (char*)lds4;
    const int tid = threadIdx.x;
    const int w = tid >> 6, lane = tid & 63, g = lane >> 4, c = lane & 15;
    const int flat = blockIdx.x;
    const int x = flat & 7;
    const int qt = (flat >> 3) & 3;
    const int a = flat >> 5;
    const size_t bh = (size_t)(a * 8 + x);
    const int q0 = qt * 128;

    bf16x8 qf[2][2];
    #pragma unroll
    for (int qs = 0; qs < 2; ++qs) {
        const unsigned short* qp = Qb + (bh * Pn + q0 + w * 32 + qs * 16 + c) * 64;
        qf[qs][0] = *(const bf16x8*)(qp + g * 8);
        qf[qs][1] = *(const bf16x8*)(qp + g * 8 + 32);
    }
    f32x4 oacc[2][4];
    #pragma unroll
    for (int qs = 0; qs < 2; ++qs)
        #pragma unroll
        for (int dt = 0; dt < 4; ++dt)
            oacc[qs][dt] = (f32x4){0.f, 0.f, 0.f, 0.f};

    const unsigned short* Kg0 = Kb + bh * (size_t)(Pn * 64);
    const unsigned short* Vg0 = Vt + bh * (size_t)(64 * Pn);

    auto stage = [&](int kt, int buf) {
        const unsigned short* Kg = Kg0 + kt * (64 * 64);
        const unsigned short* Vg = Vg0 + kt * 64;
        #pragma unroll
        for (int j = 0; j < 2; ++j) {
            int chunk = w * 128 + j * 64 + lane;
            int row = chunk >> 3, c8 = chunk & 7;
            int swc = (c8 ^ (row & 7)) << 3;
            __builtin_amdgcn_global_load_lds(
                (const __attribute__((address_space(1))) void*)(Kg + row * 64 + swc),
                (__attribute__((address_space(3))) void*)(ldsb + buf * 8192 + w * 2048 + j * 1024),
                16, 0, 0);
            __builtin_amdgcn_global_load_lds(
                (const __attribute__((address_space(1))) void*)(Vg + (size_t)row * Pn + swc),
                (__attribute__((address_space(3))) void*)(ldsb + 16384 + buf * 8192 + w * 2048 + j * 1024),
                16, 0, 0);
        }
    };

    stage(0, 0);

    #pragma unroll 2
    for (int kt = 0; kt < 8; ++kt) {
        const int cur = kt & 1;
        VMCNT(0);
        __builtin_amdgcn_s_barrier();
        __builtin_amdgcn_sched_barrier(0);
        if (kt < 7) stage(kt + 1, cur ^ 1);
        __builtin_amdgcn_sched_barrier(0);

        char* Klb = ldsb + cur * 8192;
        char* Vlb = ldsb + 16384 + cur * 8192;

        // scores (swapped): s4 = log2e*(QK/SCALE) - 30*log2e directly from MFMA
        unsigned up01[2][4], up23[2][4];
        #pragma unroll
        for (int t = 0; t < 4; ++t) {
            const int krow = t * 16 + c;
            bf16x8 kf0 = *(const bf16x8*)(Klb + krow * 128 + 16 * ((g    ) ^ (krow & 7)));
            bf16x8 kf1 = *(const bf16x8*)(Klb + krow * 128 + 16 * ((g + 4) ^ (krow & 7)));
            #pragma unroll
            for (int qs = 0; qs < 2; ++qs) {
                f32x4 s4 = {0.f, 0.f, 0.f, 0.f};
                __builtin_amdgcn_s_setprio(1);
                s4 = __builtin_amdgcn_mfma_f32_16x16x32_bf16(kf0, qf[qs][0], s4, 0, 0, 0);
                s4 = __builtin_amdgcn_mfma_f32_16x16x32_bf16(kf1, qf[qs][1], s4, 0, 0, 0);
                __builtin_amdgcn_s_setprio(0);
                float p0 = fexp2(s4[0]);
                float p1 = fexp2(s4[1]);
                float p2 = fexp2(s4[2]);
                float p3 = fexp2(s4[3]);
                up01[qs][t] = cvtpk(p0, p1);
                up23[qs][t] = cvtpk(p2, p3);
            }
        }

        // PV: build A-frags in-register via permlane swaps
        #pragma unroll
        for (int kk = 0; kk < 2; ++kk) {
            bf16x8 pa[2];
            #pragma unroll
            for (int qs = 0; qs < 2; ++qs) {
                unsigned d0 = up01[qs][2 * kk], d2 = up01[qs][2 * kk + 1];
                unsigned d1 = up23[qs][2 * kk], d3 = up23[qs][2 * kk + 1];
                asm("v_permlane32_swap_b32 %0, %1" : "+v"(d0), "+v"(d2));
                asm("v_permlane16_swap_b32 %0, %1" : "+v"(d0), "+v"(d2));
                asm("v_permlane32_swap_b32 %0, %1" : "+v"(d1), "+v"(d3));
                asm("v_permlane16_swap_b32 %0, %1" : "+v"(d1), "+v"(d3));
                uint4 uv = {d0, d1, d2, d3};
                pa[qs] = __builtin_bit_cast(bf16x8, uv);
            }
            __builtin_amdgcn_s_setprio(1);
            #pragma unroll
            for (int dt = 0; dt < 4; ++dt) {
                const int vrow = dt * 16 + c;
                bf16x8 vf = *(const bf16x8*)(Vlb + vrow * 128 + 16 * ((g + 4 * kk) ^ (vrow & 7)));
                oacc[0][dt] = __builtin_amdgcn_mfma_f32_16x16x32_bf16(pa[0], vf, oacc[0][dt], 0, 0, 0);
                oacc[1][dt] = __builtin_amdgcn_mfma_f32_16x16x32_bf16(pa[1], vf, oacc[1][dt], 0, 0, 0);
            }
            __builtin_amdgcn_s_setprio(0);
        }
    }
    __builtin_amdgcn_s_barrier();   // all waves done with K/V before reusing K area for staging

    // denom arrived in oacc[qs][3] reg r at lanes c==1 (col 49): broadcast + rcp
    float rinv[2][4];
    #pragma unroll
    for (int qs = 0; qs < 2; ++qs)
        #pragma unroll
        for (int r = 0; r < 4; ++r) {
            float s = __shfl(oacc[qs][3][r], (lane & 48) | 1);
            rinv[qs][r] = 1.0f / s;
        }
    char* stgw = ldsb + w * 4096;
    #pragma unroll
    for (int qs = 0; qs < 2; ++qs)
        #pragma unroll
        for (int dt = 0; dt < 4; ++dt)
            #pragma unroll
            for (int r = 0; r < 4; ++r) {
                int prow = qs * 16 + 4 * g + r;
                int col = dt * 16 + c;
                *(unsigned short*)(stgw + prow * 128 + ((2 * col) ^ ((prow & 7) << 4))) =
                    f2bf(oacc[qs][dt][r] * rinv[qs][r]);
            }
    LGKM0();
    __builtin_amdgcn_sched_barrier(0);
    #pragma unroll
    for (int i = 0; i < 4; ++i) {
        int chunk = i * 64 + lane;
        int row = chunk >> 3, c8 = chunk & 7;
        uint4 v = *(const uint4*)(stgw + row * 128 + 16 * (c8 ^ (row & 7)));
        size_t grow = bh * Pn + q0 + w * 32 + row;
        *(uint4*)(AO + grow * 64 + c8 * 8) = v;
    }
}

// ---------- fused out-projection + next-layer QKV; 3-buffer 2-deep prefetch
__global__ __launch_bounds__(256)
void outqkv_kernel(const unsigned short* __restrict__ AO,     // [Bc][H][P][64]
                   const unsigned short* __restrict__ Weffl,  // [8][64][64]
                   const float* __restrict__ beffl,           // [49]
                   const unsigned short* __restrict__ Wqkv,   // next layer [3][8][64][64]
                   const float* __restrict__ bq_l, const float* __restrict__ bk_l,
                   const float* __restrict__ bv_l,
                   unsigned short* __restrict__ Qb, unsigned short* __restrict__ Kb,
                   unsigned short* __restrict__ Vt,
                   unsigned short* __restrict__ xout,         // used only when last
                   int last, int b_off, int Bc) {
    // A bufs: 0 / 8192 / 16384 | W bufs: 24576 / 32768 / 40960 | stg @ 49152 (8704)
    __shared__ uint4 lds4[3616];
    __shared__ __align__(16) float blds[1536];
    __shared__ __align__(16) float bldc[64];
    char* ldsb = (char*)lds4;
    unsigned short* stg = (unsigned short*)(ldsb + 49152);
    const int tid = threadIdx.x;
    const int w = tid >> 6, lane = tid & 63, g = lane >> 4, c = lane & 15;
    const int flat = blockIdx.x;
    const int bl = flat % Bc;
    const int tile = flat / Bc;
    const int p0 = tile * 64;
    const int r0 = bl * Pn + p0;

    if (!last) {
        for (int t = tid; t < 1536; t += 256) {
            int mat = t >> 9, rem = t & 511, h = rem >> 6, o = rem & 63;
            const float* bb = (mat == 0) ? bq_l : (mat == 1) ? bk_l : bv_l;
            blds[t] = (o < 49) ? bb[h * 49 + o] : 0.f;
        }
    }
    if (tid < 64) bldc[tid] = (tid < 49) ? beffl[tid] : 0.f;

    const int chunk0 = w * 128 + lane;
    const int rowL0 = chunk0 >> 3, c8L0 = chunk0 & 7;
    const int swc0 = (c8L0 ^ (rowL0 & 7)) << 3;
    const int chunk1 = chunk0 + 64;
    const int rowL1 = chunk1 >> 3, c8L1 = chunk1 & 7;
    const int swc1 = (c8L1 ^ (rowL1 & 7)) << 3;

    auto stageW = [&](const unsigned short* Wg, int buf) {   // buf 0..2
        __builtin_amdgcn_global_load_lds(
            (const __attribute__((address_space(1))) void*)(Wg + rowL0 * 64 + swc0),
            (__attribute__((address_space(3))) void*)(ldsb + 24576 + buf * 8192 + w * 2048),
            16, 0, 0);
        __builtin_amdgcn_global_load_lds(
            (const __attribute__((address_space(1))) void*)(Wg + rowL1 * 64 + swc1),
            (__attribute__((address_space(3))) void*)(ldsb + 24576 + buf * 8192 + w * 2048 + 1024),
            16, 0, 0);
    };
    auto stageA = [&](const unsigned short* Ag, int buf) {   // buf 0..2
        __builtin_amdgcn_global_load_lds(
            (const __attribute__((address_space(1))) void*)(Ag + rowL0 * 64 + swc0),
            (__attribute__((address_space(3))) void*)(ldsb + buf * 8192 + w * 2048),
            16, 0, 0);
        __builtin_amdgcn_global_load_lds(
            (const __attribute__((address_space(1))) void*)(Ag + rowL1 * 64 + swc1),
            (__attribute__((address_space(3))) void*)(ldsb + buf * 8192 + w * 2048 + 1024),
            16, 0, 0);
    };

    // ---- Phase A: out-projection over 8 heads (swapped: D[o2=bt*16+4g+r][p=w*16+c])
    f32x4 acc[4];
    #pragma unroll
    for (int bt = 0; bt < 4; ++bt) acc[bt] = (f32x4){0.f, 0.f, 0.f, 0.f};

    stageA(AO + (((size_t)bl * Hn + 0) * Pn + p0) * 64, 0);
    stageW(Weffl, 0);
    stageA(AO + (((size_t)bl * Hn + 1) * Pn + p0) * 64, 1);
    stageW(Weffl + 4096, 1);
    for (int h = 0; h < Hn; ++h) {
        const int cur = h % 3;
        if (h < 7) { VMCNT(4); } else { VMCNT(0); }
        __builtin_amdgcn_s_barrier();
        __builtin_amdgcn_sched_barrier(0);
        if (h < 6) {
            stageA(AO + (((size_t)bl * Hn + h + 2) * Pn + p0) * 64, (h + 2) % 3);
            stageW(Weffl + (size_t)(h + 2) * 4096, (h + 2) % 3);
        }
        __builtin_amdgcn_sched_barrier(0);
        char* Alb = ldsb + cur * 8192;
        char* Wlb = ldsb + 24576 + cur * 8192;
        const int rowa = w * 16 + c;
        bf16x8 a0 = *(const bf16x8*)(Alb + rowa * 128 + 16 * ((g    ) ^ (c & 7)));
        bf16x8 a1 = *(const bf16x8*)(Alb + rowa * 128 + 16 * ((g + 4) ^ (c & 7)));
        #pragma unroll
        for (int bt = 0; bt < 4; ++bt) {
            int rowb = bt * 16 + c;
            bf16x8 w0 = *(const bf16x8*)(Wlb + rowb * 128 + 16 * ((g    ) ^ (rowb & 7)));
            bf16x8 w1 = *(const bf16x8*)(Wlb + rowb * 128 + 16 * ((g + 4) ^ (rowb & 7)));
            acc[bt] = __builtin_amdgcn_mfma_f32_16x16x32_bf16(w0, a0, acc[bt], 0, 0, 0);
            acc[bt] = __builtin_amdgcn_mfma_f32_16x16x32_bf16(w1, a1, acc[bt], 0, 0, 0);
        }
    }

    const int p = w * 16 + c;
    if (last) {
        __syncthreads();
        #pragma unroll
        for (int bt = 0; bt < 4; ++bt) {
            f32x4 bb4 = *(const f32x4*)(bldc + bt * 16 + 4 * g);
            uint2 pk = {cvtpk(acc[bt][0] + bb4[0], acc[bt][1] + bb4[1]),
                        cvtpk(acc[bt][2] + bb4[2], acc[bt][3] + bb4[3])};
            *(uint2*)((char*)stg + p * 136 + (bt * 16 + 4 * g) * 2) = pk;
        }
        LGKM0();
        __syncthreads();
        #pragma unroll
        for (int i = 0; i < 4; ++i) {
            int chunk = tid + i * 256;
            int prow = chunk >> 4, c4 = chunk & 15;
            uint2 v = *(const uint2*)((const char*)stg + prow * 136 + c4 * 8);
            size_t grow = (size_t)(b_off + bl) * Pn + p0 + prow;
            *(uint2*)(xout + grow * 64 + c4 * 4) = v;
        }
        return;
    }

    // ---- Phase B: x-tile (bf16) into A buf0 (last read at h==6; all waves past h==7 top barrier)
    #pragma unroll
    for (int bt = 0; bt < 4; ++bt) {
        f32x4 bb4 = *(const f32x4*)(bldc + bt * 16 + 4 * g);
        uint2 pk = {cvtpk(acc[bt][0] + bb4[0], acc[bt][1] + bb4[1]),
                    cvtpk(acc[bt][2] + bb4[2], acc[bt][3] + bb4[3])};
        *(uint2*)(ldsb + p * 128 + ((2 * (bt * 16 + 4 * g)) ^ ((p & 7) << 4))) = pk;
    }
    stageW(Wqkv, 0);             // W buf0 last read at h==6 -> safe
    LGKM0();
    __builtin_amdgcn_s_barrier();       // all waves done h==7; x-tile visible
    __builtin_amdgcn_sched_barrier(0);
    stageW(Wqkv + 4096, 1);      // W buf1 last read at h==7; safe now

    const int rowa = w * 16 + c;
    bf16x8 a0 = *(const bf16x8*)(ldsb + rowa * 128 + 16 * ((g    ) ^ (c & 7)));
    bf16x8 a1 = *(const bf16x8*)(ldsb + rowa * 128 + 16 * ((g + 4) ^ (c & 7)));

    // ---- Phase C: next-layer QKV, 3-buffer 2-deep prefetch
    // VMCNT(6): need L(panel) (2 loads, issued at panel-2); younger ops at this point are
    // L(panel+1)x2 + S(panel-1)x4 = 6 -> waits exactly for L(panel) without draining stores.
    for (int panel = 0; panel < 24; ++panel) {
        const int mat = panel >> 3, h = panel & 7;
        const int cur = panel % 3;
        if (panel < 23) { VMCNT(6); } else { VMCNT(0); }
        __builtin_amdgcn_s_barrier();
        __builtin_amdgcn_sched_barrier(0);
        if (panel < 22) stageW(Wqkv + (size_t)(panel + 2) * 4096, (panel + 2) % 3);
        __builtin_amdgcn_sched_barrier(0);
        char* Wlb = ldsb + 24576 + cur * 8192;

        f32x4 pacc[4];
        #pragma unroll
        for (int bt = 0; bt < 4; ++bt) pacc[bt] = (f32x4){0.f, 0.f, 0.f, 0.f};
        const float* bbB = blds + mat * 512 + h * 64;

        if (mat < 2) {
            #pragma unroll
            for (int bt = 0; bt < 4; ++bt) {
                int rowb = bt * 16 + c;
                bf16x8 w0 = *(const bf16x8*)(Wlb + rowb * 128 + 16 * ((g    ) ^ (rowb & 7)));
                bf16x8 w1 = *(const bf16x8*)(Wlb + rowb * 128 + 16 * ((g + 4) ^ (rowb & 7)));
                pacc[bt] = __builtin_amdgcn_mfma_f32_16x16x32_bf16(w0, a0, pacc[bt], 0, 0, 0);
                pacc[bt] = __builtin_amdgcn_mfma_f32_16x16x32_bf16(w1, a1, pacc[bt], 0, 0, 0);
            }
            #pragma unroll
            for (int bt = 0; bt < 4; ++bt) {
                f32x4 bb4 = *(const f32x4*)(bbB + bt * 16 + 4 * g);
                float v0 = pacc[bt][0] + bb4[0];
                float v1 = pacc[bt][1] + bb4[1];
                float v2 = pacc[bt][2] + bb4[2];
                float v3 = pacc[bt][3] + bb4[3];
                if (mat == 0) { v0 *= C1F; v1 *= C1F; v2 *= C1F; v3 *= C1F; }
                if (bt == 3) {
                    float q49 = (mat == 0) ? -C2F : 1.0f;
                    bool g0 = (g == 0);
                    v0 = g0 ? v0 : 0.f;
                    v1 = g0 ? q49 : 0.f;
                    v2 = 0.f; v3 = 0.f;
                }
                uint2 pk = {cvtpk(v0, v1), cvtpk(v2, v3)};
                *(uint2*)((char*)stg + p * 136 + (bt * 16 + 4 * g) * 2) = pk;
            }
        } else {
            #pragma unroll
            for (int bt = 0; bt < 4; ++bt) {
                int rowb = bt * 16 + c;
                bf16x8 w0 = *(const bf16x8*)(Wlb + rowb * 128 + 16 * ((g    ) ^ (rowb & 7)));
                bf16x8 w1 = *(const bf16x8*)(Wlb + rowb * 128 + 16 * ((g + 4) ^ (rowb & 7)));
                pacc[bt] = __builtin_amdgcn_mfma_f32_16x16x32_bf16(a0, w0, pacc[bt], 0, 0, 0);
                pacc[bt] = __builtin_amdgcn_mfma_f32_16x16x32_bf16(a1, w1, pacc[bt], 0, 0, 0);
            }
            #pragma unroll
            for (int bt = 0; bt < 4; ++bt) {
                int d = bt * 16 + c;
                float bbd = bbB[d];
                float v0 = pacc[bt][0] + bbd;
                float v1 = pacc[bt][1] + bbd;
                float v2 = pacc[bt][2] + bbd;
                float v3 = pacc[bt][3] + bbd;
                if (bt == 3) {
                    bool is49 = (c == 1);
                    v0 = is49 ? 1.0f : v0;
                    v1 = is49 ? 1.0f : v1;
                    v2 = is49 ? 1.0f : v2;
                    v3 = is49 ? 1.0f : v3;
                }
                uint2 pk = {cvtpk(v0, v1), cvtpk(v2, v3)};
                *(uint2*)((char*)stg + d * 136 + (w * 16 + 4 * g) * 2) = pk;
            }
        }
        LGKM0();
        __builtin_amdgcn_s_barrier();

        if (mat < 2) {
            unsigned short* outp = (mat == 0) ? Qb : Kb;
            #pragma unroll
            for (int i = 0; i < 4; ++i) {
                int chunk = tid + i * 256;
                int prow = chunk >> 4, c4 = chunk & 15;
                uint2 v = *(const uint2*)((const char*)stg + prow * 136 + c4 * 8);
                int rr = r0 + prow;
                int bl2 = rr >> 9, pp = rr & 511;
                *(uint2*)(outp + (((size_t)bl2 * Hn + h) * Pn + pp) * 64 + c4 * 4) = v;
            }
        } else {
            #pragma unroll
            for (int i = 0; i < 4; ++i) {
                int chunk = tid + i * 256;
                int drow = chunk >> 4, c4 = chunk & 15;
                uint2 v = *(const uint2*)((const char*)stg + drow * 136 + c4 * 8);
                *(uint2*)(Vt + (((size_t)bl * Hn + h) * 64 + drow) * Pn + p0 + c4 * 4) = v;
            }
        }
    }
}

// ---------- mean-pool over P (bf16 input)
__global__ __launch_bounds__(256)
void pool_kernel(const unsigned short* __restrict__ x, float* __restrict__ pooled) {
    __shared__ float red[256];
    const int b = blockIdx.x;
    const int tid = threadIdx.x;
    const int ps = tid >> 6, d = tid & 63;
    float s = 0.f;
    for (int p = ps; p < Pn; p += 4) s += bf2f(x[((size_t)b * Pn + p) * 64 + d]);
    red[tid] = s;
    __syncthreads();
    if (tid < 64) {
        float t = red[tid] + red[tid + 64] + red[tid + 128] + red[tid + 192];
        if (tid < 49) pooled[b * 49 + tid] = t * (1.0f / Pn);
    }
}

// ---------- MLP + log-softmax + NLL
__global__ __launch_bounds__(64)
void head_kernel(const float* __restrict__ pooled, const int* __restrict__ labels,
                 const float* __restrict__ W1, const float* __restrict__ b1,
                 const float* __restrict__ W2, const float* __restrict__ b2,
                 float* __restrict__ out) {
    __shared__ float lloss[64];
    const int b = threadIdx.x;
    float pr[49];
    #pragma unroll
    for (int i = 0; i < 49; ++i) pr[i] = pooled[b * 49 + i];
    float hh[25];
    for (int j = 0; j < 25; ++j) {
        float s = b1[j];
        for (int i = 0; i < 49; ++i) s = fmaf(pr[i], W1[j * 49 + i], s);
        hh[j] = fmaxf(s, 0.f);
    }
    float lg[10];
    float m = -1e30f;
    for (int k = 0; k < 10; ++k) {
        float s = b2[k];
        for (int j = 0; j < 25; ++j) s = fmaf(hh[j], W2[k * 25 + j], s);
        lg[k] = s;
        m = fmaxf(m, s);
    }
    float se = 0.f;
    for (int k = 0; k < 10; ++k) se += __expf(lg[k] - m);
    float lse = m + __logf(se);
    int lbl = labels[b];
    lloss[b] = lse - lg[lbl];
    __syncthreads();
    if (b == 0) {
        float s = 0.f;
        for (int i = 0; i < 64; ++i) s += lloss[i];
        out[0] = s * (1.0f / 64.0f);
    }
}

extern "C" void kernel_launch(void* const* d_in, const int* in_sizes, int n_in,
                              void* d_out, int out_size, void* d_ws, size_t ws_size,
                              hipStream_t stream) {
    const float* emb    = (const float*)d_in[0];
    const int*   labels = (const int*)d_in[1];
    const float* Wq = (const float*)d_in[2];
    const float* bq = (const float*)d_in[3];
    const float* Wk = (const float*)d_in[4];
    const float* bk = (const float*)d_in[5];
    const float* Wv = (const float*)d_in[6];
    const float* bv = (const float*)d_in[7];
    const float* Wh = (const float*)d_in[8];
    const float* bhp = (const float*)d_in[9];
    const float* Wout = (const float*)d_in[10];
    const float* W1 = (const float*)d_in[11];
    const float* b1 = (const float*)d_in[12];
    const float* W2 = (const float*)d_in[13];
    const float* b2 = (const float*)d_in[14];
    float* out = (float*)d_out;

    char* base = (char*)d_ws;
    size_t off = 0;
    auto alloc = [&](size_t bytes) {
        off = (off + 255) & ~(size_t)255;
        char* p = base + off;
        off += bytes;
        return p;
    };

    unsigned short* WqkvB = (unsigned short*)alloc((size_t)Ln * 3 * Hn * 4096 * 2);
    unsigned short* WeffB = (unsigned short*)alloc((size_t)Ln * Hn * 4096 * 2);
    float*          beffB = (float*)alloc((size_t)Ln * 49 * 4);
    unsigned short* xA    = (unsigned short*)alloc((size_t)Bn * Pn * 64 * 2);
    unsigned short* xB    = (unsigned short*)alloc((size_t)Bn * Pn * 64 * 2);
    float*          pooled = (float*)alloc((size_t)Bn * 49 * 4);

    const size_t per_b = 4 * ((size_t)Hn * Pn * 64 * 2);   // Q + K + Vt + AO bf16
    size_t fixed = (off + 255) & ~(size_t)255;
    int Bc = Bn;
    while (Bc > 8 && fixed + (size_t)Bc * per_b + 4096 > ws_size) Bc >>= 1;

    unsigned short* Qb  = (unsigned short*)alloc((size_t)Bc * Hn * Pn * 64 * 2);
    unsigned short* Kb  = (unsigned short*)alloc((size_t)Bc * Hn * Pn * 64 * 2);
    unsigned short* Vtb = (unsigned short*)alloc((size_t)Bc * Hn * Pn * 64 * 2);
    unsigned short* AOb = (unsigned short*)alloc((size_t)Bc * Hn * Pn * 64 * 2);

    prep_wqkv_kernel<<<(Ln * 3 * Hn * 4096 + 255) / 256, 256, 0, stream>>>(Wq, Wk, Wv, WqkvB);
    prep_weff_kernel<<<(Ln * Hn * 4096 + Ln * 49 + 255) / 256, 256, 0, stream>>>(Wh, bhp, Wout, WeffB, beffB);
    cast_x_kernel<<<(Bn * Pn * 64) / 256, 256, 0, stream>>>(emb, xA);

    for (int b0 = 0; b0 < Bn; b0 += Bc) {
        qkv_mfma_kernel<<<Bc * 8, 256, 0, stream>>>(
            xA, WqkvB, bq, bk, bv, Qb, Kb, Vtb, b0, Bc);
        for (int l = 0; l < Ln; ++l) {
            attn_head_kernel<<<Bc * 32, 256, 0, stream>>>(Qb, Kb, Vtb, AOb, Bc);
            int last = (l == Ln - 1) ? 1 : 0;
            int ln = last ? 0 : (l + 1);
            outqkv_kernel<<<Bc * 8, 256, 0, stream>>>(
                AOb,
                WeffB + (size_t)l * Hn * 4096,
                beffB + (size_t)l * 49,
                WqkvB + (size_t)ln * 3 * Hn * 4096,
                bq + (size_t)ln * Hn * 49,
                bk + (size_t)ln * Hn * 49,
                bv + (size_t)ln * Hn * 49,
                Qb, Kb, Vtb, xB, last, b0, Bc);
        }
    }

    pool_kernel<<<Bn, 256, 0, stream>>>(xB, pooled);
    head_kernel<<<1, 64, 0, stream>>>(pooled, labels, W1, b1, W2, b2, out);
}

// Round 15
// 487.311 us; speedup vs baseline: 1.5618x; 1.0258x over previous
//
#include <hip/hip_runtime.h>
#include <hip/hip_bf16.h>
#include <math.h>

#define Bn 64
#define Pn 512
#define Hn 8
#define Ln 6

typedef __bf16 bf16x8 __attribute__((ext_vector_type(8)));
typedef float f32x4 __attribute__((ext_vector_type(4)));

#define VMCNT(n) asm volatile("s_waitcnt vmcnt(" #n ")" ::: "memory")
#define LGKM0()  asm volatile("s_waitcnt lgkmcnt(0)" ::: "memory")

static __device__ __forceinline__ unsigned short f2bf(float f) {
    return __builtin_bit_cast(unsigned short, __float2bfloat16(f));
}
static __device__ __forceinline__ float bf2f(unsigned short v) {
    unsigned int u = ((unsigned int)v) << 16;
    return __builtin_bit_cast(float, u);
}
static __device__ __forceinline__ float fexp2(float x) {
    float r;
    asm("v_exp_f32 %0, %1" : "=v"(r) : "v"(x));
    return r;
}
static __device__ __forceinline__ unsigned cvtpk(float a, float b) {
    unsigned r;
    asm("v_cvt_pk_bf16_f32 %0, %1, %2" : "=v"(r) : "v"(a), "v"(b));
    return r;
}

#define C1F (1.4426950408889634f / 7.000001f)   // log2(e)/SCALE
#define C2F 43.2808512f                         // 30*log2(e)

// ---------- prep: cast/pad Wq,Wk,Wv -> [L][3][H][64 o][64 i] bf16 (zero-padded)
__global__ __launch_bounds__(256)
void prep_wqkv_kernel(const float* __restrict__ Wq, const float* __restrict__ Wk,
                      const float* __restrict__ Wv, unsigned short* __restrict__ out) {
    int idx = blockIdx.x * 256 + threadIdx.x;
    if (idx >= Ln * 3 * Hn * 4096) return;
    int i = idx & 63, o = (idx >> 6) & 63, h = (idx >> 12) & 7, t = idx >> 15;
    int mat = t % 3, l = t / 3;
    float v = 0.f;
    if (o < 49 && i < 49) {
        const float* src = (mat == 0) ? Wq : (mat == 1) ? Wk : Wv;
        v = src[(((size_t)(l * Hn + h) * 49) + o) * 49 + i];
    }
    out[idx] = f2bf(v);
}

// ---------- prep: Weff[l][h][o2 64][o 64] bf16 = sum_dd Wh[l,h,dd,o]*Wout[l,o2,h*49+dd]
__global__ __launch_bounds__(256)
void prep_weff_kernel(const float* __restrict__ Wh, const float* __restrict__ bh,
                      const float* __restrict__ Wout,
                      unsigned short* __restrict__ Weff, float* __restrict__ beff) {
    const int NW = Ln * Hn * 4096;
    int idx = blockIdx.x * 256 + threadIdx.x;
    if (idx < NW) {
        int o = idx & 63, o2 = (idx >> 6) & 63, h = (idx >> 12) & 7, l = idx >> 15;
        float s = 0.f;
        if (o < 49 && o2 < 49) {
            const float* wh = Wh + ((size_t)(l * Hn + h) * 49) * 49 + o;   // [dd] stride 49
            const float* wo = Wout + ((size_t)l * 49 + o2) * 392 + h * 49; // [dd]
            for (int dd = 0; dd < 49; ++dd) s = fmaf(wh[dd * 49], wo[dd], s);
        }
        Weff[idx] = f2bf(s);
    } else if (idx < NW + Ln * 49) {
        int j = idx - NW;
        int l = j / 49, o2 = j % 49;
        const float* wo = Wout + ((size_t)l * 49 + o2) * 392;
        const float* bhl = bh + (size_t)l * 392;
        float s = 0.f;
        for (int cc = 0; cc < 392; ++cc) s = fmaf(bhl[cc], wo[cc], s);
        beff[j] = s;
    }
}

// ---------- prep: cast embedding -> x_bf [32768][64] padded
__global__ __launch_bounds__(256)
void cast_x_kernel(const float* __restrict__ emb, unsigned short* __restrict__ xbf) {
    int idx = blockIdx.x * 256 + threadIdx.x;
    int row = idx >> 6, col = idx & 63;
    float v = (col < 49) ? emb[(size_t)row * 49 + col] : 0.f;
    xbf[idx] = f2bf(v);
}

// ---------- QKV via MFMA (layer 0 only)
// Q pre-scaled by log2e/SCALE with Q[:,49] = -30*log2e; K[:,49] = 1; V^T[49][:] = 1.
__global__ __launch_bounds__(256)
void qkv_mfma_kernel(const unsigned short* __restrict__ xbf,
                     const unsigned short* __restrict__ Wqkv,
                     const float* __restrict__ bq_l, const float* __restrict__ bk_l,
                     const float* __restrict__ bv_l,
                     unsigned short* __restrict__ Qb, unsigned short* __restrict__ Kb,
                     unsigned short* __restrict__ Vt,
                     int b_off, int Bc) {
    __shared__ uint4 xlb4[512];
    __shared__ uint4 wlb4[512];
    __shared__ __align__(16) unsigned short stg[64 * 68];
    __shared__ __align__(16) float blds[1536];
    char* xlb = (char*)xlb4;
    char* wlb = (char*)wlb4;
    const int tid = threadIdx.x;
    const int w = tid >> 6, lane = tid & 63, g = lane >> 4, c = lane & 15;
    const int flat = blockIdx.x;
    const int bl = flat % Bc;
    const int tile = flat / Bc;
    const int r0 = bl * Pn + tile * 64;

    for (int t = tid; t < 1536; t += 256) {
        int mat = t >> 9, rem = t & 511, h = rem >> 6, o = rem & 63;
        const float* bb = (mat == 0) ? bq_l : (mat == 1) ? bk_l : bv_l;
        blds[t] = (o < 49) ? bb[h * 49 + o] : 0.f;
    }
    {
        const unsigned short* xg = xbf + ((size_t)b_off * Pn + r0) * 64;
        #pragma unroll
        for (int i = 0; i < 2; ++i) {
            int chunk = tid + i * 256;
            int row = chunk >> 3, c8 = chunk & 7;
            *(uint4*)(xlb + row * 128 + 16 * (c8 ^ (row & 7))) =
                *(const uint4*)(xg + row * 64 + c8 * 8);
        }
    }
    __syncthreads();

    const int rowa = w * 16 + c;
    bf16x8 a0 = *(const bf16x8*)(xlb + rowa * 128 + 16 * ((g    ) ^ (c & 7)));
    bf16x8 a1 = *(const bf16x8*)(xlb + rowa * 128 + 16 * ((g + 4) ^ (c & 7)));

    for (int panel = 0; panel < 24; ++panel) {
        const int mat = panel >> 3, h = panel & 7;
        const unsigned short* wg = Wqkv + (size_t)panel * 4096;
        #pragma unroll
        for (int i = 0; i < 2; ++i) {
            int chunk = tid + i * 256;
            int row = chunk >> 3, c8 = chunk & 7;
            *(uint4*)(wlb + row * 128 + 16 * (c8 ^ (row & 7))) =
                *(const uint4*)(wg + row * 64 + c8 * 8);
        }
        __syncthreads();

        f32x4 acc[4];
        #pragma unroll
        for (int bt = 0; bt < 4; ++bt) acc[bt] = (f32x4){0.f, 0.f, 0.f, 0.f};
        const float* bbB = blds + mat * 512 + h * 64;

        if (mat < 2) {
            // swapped: D[o=bt*16+4g+r][p=w*16+c] -> 4 consecutive o per lane
            #pragma unroll
            for (int bt = 0; bt < 4; ++bt) {
                int rowb = bt * 16 + c;
                bf16x8 w0 = *(const bf16x8*)(wlb + rowb * 128 + 16 * ((g    ) ^ (rowb & 7)));
                bf16x8 w1 = *(const bf16x8*)(wlb + rowb * 128 + 16 * ((g + 4) ^ (rowb & 7)));
                acc[bt] = __builtin_amdgcn_mfma_f32_16x16x32_bf16(w0, a0, acc[bt], 0, 0, 0);
                acc[bt] = __builtin_amdgcn_mfma_f32_16x16x32_bf16(w1, a1, acc[bt], 0, 0, 0);
            }
            const int p = w * 16 + c;
            #pragma unroll
            for (int bt = 0; bt < 4; ++bt) {
                f32x4 bb4 = *(const f32x4*)(bbB + bt * 16 + 4 * g);
                float v0 = acc[bt][0] + bb4[0];
                float v1 = acc[bt][1] + bb4[1];
                float v2 = acc[bt][2] + bb4[2];
                float v3 = acc[bt][3] + bb4[3];
                if (mat == 0) { v0 *= C1F; v1 *= C1F; v2 *= C1F; v3 *= C1F; }
                if (bt == 3) {
                    float q49 = (mat == 0) ? -C2F : 1.0f;
                    bool g0 = (g == 0);          // o = 48+4g+r
                    v0 = g0 ? v0 : 0.f;
                    v1 = g0 ? q49 : 0.f;
                    v2 = 0.f; v3 = 0.f;
                }
                uint2 pk = {cvtpk(v0, v1), cvtpk(v2, v3)};
                *(uint2*)((char*)stg + p * 136 + (bt * 16 + 4 * g) * 2) = pk;
            }
        } else {
            // original: D[p=w*16+4g+r][o=bt*16+c] -> 4 consecutive p per lane (V^T)
            #pragma unroll
            for (int bt = 0; bt < 4; ++bt) {
                int rowb = bt * 16 + c;
                bf16x8 w0 = *(const bf16x8*)(wlb + rowb * 128 + 16 * ((g    ) ^ (rowb & 7)));
                bf16x8 w1 = *(const bf16x8*)(wlb + rowb * 128 + 16 * ((g + 4) ^ (rowb & 7)));
                acc[bt] = __builtin_amdgcn_mfma_f32_16x16x32_bf16(a0, w0, acc[bt], 0, 0, 0);
                acc[bt] = __builtin_amdgcn_mfma_f32_16x16x32_bf16(a1, w1, acc[bt], 0, 0, 0);
            }
            #pragma unroll
            for (int bt = 0; bt < 4; ++bt) {
                int d = bt * 16 + c;
                float bbd = bbB[d];
                float v0 = acc[bt][0] + bbd;
                float v1 = acc[bt][1] + bbd;
                float v2 = acc[bt][2] + bbd;
                float v3 = acc[bt][3] + bbd;
                if (bt == 3) {
                    bool is49 = (c == 1);        // d = 48+c
                    v0 = is49 ? 1.0f : v0;
                    v1 = is49 ? 1.0f : v1;
                    v2 = is49 ? 1.0f : v2;
                    v3 = is49 ? 1.0f : v3;
                }
                uint2 pk = {cvtpk(v0, v1), cvtpk(v2, v3)};
                *(uint2*)((char*)stg + d * 136 + (w * 16 + 4 * g) * 2) = pk;
            }
        }
        __syncthreads();

        if (mat < 2) {
            unsigned short* outp = (mat == 0) ? Qb : Kb;
            #pragma unroll
            for (int i = 0; i < 4; ++i) {
                int chunk = tid + i * 256;
                int prow = chunk >> 4, c4 = chunk & 15;
                uint2 v = *(const uint2*)((const char*)stg + prow * 136 + c4 * 8);
                int rr = r0 + prow;
                int bl2 = rr >> 9, p = rr & 511;
                *(uint2*)(outp + (((size_t)bl2 * Hn + h) * Pn + p) * 64 + c4 * 4) = v;
            }
        } else {
            const int bl2 = r0 >> 9, p0 = r0 & 511;
            #pragma unroll
            for (int i = 0; i < 4; ++i) {
                int chunk = tid + i * 256;
                int drow = chunk >> 4, c4 = chunk & 15;
                uint2 v = *(const uint2*)((const char*)stg + drow * 136 + c4 * 8);
                *(uint2*)(Vt + (((size_t)bl2 * Hn + h) * 64 + drow) * Pn + p0 + c4 * 4) = v;
            }
        }
        __syncthreads();
    }
}

// ---------- per-head attention: 8 waves x 256 q-rows; async dbuf; in-register P; ones-row denom
// __launch_bounds__(512, 2): 256-VGPR budget per wave -> no spill (round-11 lesson).
__global__ __launch_bounds__(512, 2)
void attn_head_kernel(const unsigned short* __restrict__ Qb,
                      const unsigned short* __restrict__ Kb,
                      const unsigned short* __restrict__ Vt,
                      unsigned short* __restrict__ AO,   // [Bc][H][P][64] bf16
                      int Bc) {
    // 32 KiB: K dbuf 2x8K | V dbuf 2x8K  (epilogue staging reuses whole area)
    __shared__ uint4 lds4[2048];
    char* ldsb = (char*)lds4;
    const int tid = threadIdx.x;
    const int w = tid >> 6, lane = tid & 63, g = lane >> 4, c = lane & 15;
    const int flat = blockIdx.x;
    const int x = flat & 7;
    const int qt = (flat >> 3) & 1;
    const int a = flat >> 4;
    const size_t bh = (size_t)(a * 8 + x);
    const int q0 = qt * 256;

    bf16x8 qf[2][2];
    #pragma unroll
    for (int qs = 0; qs < 2; ++qs) {
        const unsigned short* qp = Qb + (bh * Pn + q0 + w * 32 + qs * 16 + c) * 64;
        qf[qs][0] = *(const bf16x8*)(qp + g * 8);
        qf[qs][1] = *(const bf16x8*)(qp + g * 8 + 32);
    }
    f32x4 oacc[2][4];
    #pragma unroll
    for (int qs = 0; qs < 2; ++qs)
        #pragma unroll
        for (int dt = 0; dt < 4; ++dt)
            oacc[qs][dt] = (f32x4){0.f, 0.f, 0.f, 0.f};

    const unsigned short* Kg0 = Kb + bh * (size_t)(Pn * 64);
    const unsigned short* Vg0 = Vt + bh * (size_t)(64 * Pn);

    // 512 threads: each stages one 16B K chunk + one 16B V chunk per tile
    const int rowS = tid >> 3, c8S = tid & 7;
    const int swcS = (c8S ^ (rowS & 7)) << 3;
    auto stage = [&](int kt, int buf) {
        const unsigned short* Kg = Kg0 + kt * (64 * 64);
        const unsigned short* Vg = Vg0 + kt * 64;
        __builtin_amdgcn_global_load_lds(
            (const __attribute__((address_space(1))) void*)(Kg + rowS * 64 + swcS),
            (__attribute__((address_space(3))) void*)(ldsb + buf * 8192 + w * 1024),
            16, 0, 0);
        __builtin_amdgcn_global_load_lds(
            (const __attribute__((address_space(1))) void*)(Vg + (size_t)rowS * Pn + swcS),
            (__attribute__((address_space(3))) void*)(ldsb + 16384 + buf * 8192 + w * 1024),
            16, 0, 0);
    };

    stage(0, 0);

    #pragma unroll 2
    for (int kt = 0; kt < 8; ++kt) {
        const int cur = kt & 1;
        VMCNT(0);
        __builtin_amdgcn_s_barrier();
        __builtin_amdgcn_sched_barrier(0);
        if (kt < 7) stage(kt + 1, cur ^ 1);
        __builtin_amdgcn_sched_barrier(0);

        char* Klb = ldsb + cur * 8192;
        char* Vlb = ldsb + 16384 + cur * 8192;

        // scores (swapped): s4 = log2e*(QK/SCALE) - 30*log2e directly from MFMA
        unsigned up01[2][4], up23[2][4];
        #pragma unroll
        for (int t = 0; t < 4; ++t) {
            const int krow = t * 16 + c;
            bf16x8 kf0 = *(const bf16x8*)(Klb + krow * 128 + 16 * ((g    ) ^ (krow & 7)));
            bf16x8 kf1 = *(const bf16x8*)(Klb + krow * 128 + 16 * ((g + 4) ^ (krow & 7)));
            #pragma unroll
            for (int qs = 0; qs < 2; ++qs) {
                f32x4 s4 = {0.f, 0.f, 0.f, 0.f};
                __builtin_amdgcn_s_setprio(1);
                s4 = __builtin_amdgcn_mfma_f32_16x16x32_bf16(kf0, qf[qs][0], s4, 0, 0, 0);
                s4 = __builtin_amdgcn_mfma_f32_16x16x32_bf16(kf1, qf[qs][1], s4, 0, 0, 0);
                __builtin_amdgcn_s_setprio(0);
                float p0 = fexp2(s4[0]);
                float p1 = fexp2(s4[1]);
                float p2 = fexp2(s4[2]);
                float p3 = fexp2(s4[3]);
                up01[qs][t] = cvtpk(p0, p1);
                up23[qs][t] = cvtpk(p2, p3);
            }
        }

        // PV: build A-frags in-register via permlane swaps
        #pragma unroll
        for (int kk = 0; kk < 2; ++kk) {
            bf16x8 pa[2];
            #pragma unroll
            for (int qs = 0; qs < 2; ++qs) {
                unsigned d0 = up01[qs][2 * kk], d2 = up01[qs][2 * kk + 1];
                unsigned d1 = up23[qs][2 * kk], d3 = up23[qs][2 * kk + 1];
                asm("v_permlane32_swap_b32 %0, %1" : "+v"(d0), "+v"(d2));
                asm("v_permlane16_swap_b32 %0, %1" : "+v"(d0), "+v"(d2));
                asm("v_permlane32_swap_b32 %0, %1" : "+v"(d1), "+v"(d3));
                asm("v_permlane16_swap_b32 %0, %1" : "+v"(d1), "+v"(d3));
                uint4 uv = {d0, d1, d2, d3};
                pa[qs] = __builtin_bit_cast(bf16x8, uv);
            }
            __builtin_amdgcn_s_setprio(1);
            #pragma unroll
            for (int dt = 0; dt < 4; ++dt) {
                const int vrow = dt * 16 + c;
                bf16x8 vf = *(const bf16x8*)(Vlb + vrow * 128 + 16 * ((g + 4 * kk) ^ (vrow & 7)));
                oacc[0][dt] = __builtin_amdgcn_mfma_f32_16x16x32_bf16(pa[0], vf, oacc[0][dt], 0, 0, 0);
                oacc[1][dt] = __builtin_amdgcn_mfma_f32_16x16x32_bf16(pa[1], vf, oacc[1][dt], 0, 0, 0);
            }
            __builtin_amdgcn_s_setprio(0);
        }
    }
    __builtin_amdgcn_s_barrier();   // all waves done with K/V before reusing LDS for staging

    // denom arrived in oacc[qs][3] reg r at lanes c==1 (col 49): broadcast + rcp
    float rinv[2][4];
    #pragma unroll
    for (int qs = 0; qs < 2; ++qs)
        #pragma unroll
        for (int r = 0; r < 4; ++r) {
            float s = __shfl(oacc[qs][3][r], (lane & 48) | 1);
            rinv[qs][r] = 1.0f / s;
        }
    char* stgw = ldsb + w * 4096;
    #pragma unroll
    for (int qs = 0; qs < 2; ++qs)
        #pragma unroll
        for (int dt = 0; dt < 4; ++dt)
            #pragma unroll
            for (int r = 0; r < 4; ++r) {
                int prow = qs * 16 + 4 * g + r;
                int col = dt * 16 + c;
                *(unsigned short*)(stgw + prow * 128 + ((2 * col) ^ ((prow & 7) << 4))) =
                    f2bf(oacc[qs][dt][r] * rinv[qs][r]);
            }
    LGKM0();
    __builtin_amdgcn_sched_barrier(0);
    #pragma unroll
    for (int i = 0; i < 4; ++i) {
        int chunk = i * 64 + lane;
        int row = chunk >> 3, c8 = chunk & 7;
        uint4 v = *(const uint4*)(stgw + row * 128 + 16 * (c8 ^ (row & 7)));
        size_t grow = bh * Pn + q0 + w * 32 + row;
        *(uint4*)(AO + grow * 64 + c8 * 8) = v;
    }
}

// ---------- fused out-projection + next-layer QKV; 3-buffer 2-deep prefetch
__global__ __launch_bounds__(256)
void outqkv_kernel(const unsigned short* __restrict__ AO,     // [Bc][H][P][64]
                   const unsigned short* __restrict__ Weffl,  // [8][64][64]
                   const float* __restrict__ beffl,           // [49]
                   const unsigned short* __restrict__ Wqkv,   // next layer [3][8][64][64]
                   const float* __restrict__ bq_l, const float* __restrict__ bk_l,
                   const float* __restrict__ bv_l,
                   unsigned short* __restrict__ Qb, unsigned short* __restrict__ Kb,
                   unsigned short* __restrict__ Vt,
                   unsigned short* __restrict__ xout,         // used only when last
                   int last, int b_off, int Bc) {
    // A bufs: 0 / 8192 / 16384 | W bufs: 24576 / 32768 / 40960 | stg @ 49152 (8704)
    __shared__ uint4 lds4[3616];
    __shared__ __align__(16) float blds[1536];
    __shared__ __align__(16) float bldc[64];
    char* ldsb = (char*)lds4;
    unsigned short* stg = (unsigned short*)(ldsb + 49152);
    const int tid = threadIdx.x;
    const int w = tid >> 6, lane = tid & 63, g = lane >> 4, c = lane & 15;
    const int flat = blockIdx.x;
    const int bl = flat % Bc;
    const int tile = flat / Bc;
    const int p0 = tile * 64;
    const int r0 = bl * Pn + p0;

    if (!last) {
        for (int t = tid; t < 1536; t += 256) {
            int mat = t >> 9, rem = t & 511, h = rem >> 6, o = rem & 63;
            const float* bb = (mat == 0) ? bq_l : (mat == 1) ? bk_l : bv_l;
            blds[t] = (o < 49) ? bb[h * 49 + o] : 0.f;
        }
    }
    if (tid < 64) bldc[tid] = (tid < 49) ? beffl[tid] : 0.f;

    const int chunk0 = w * 128 + lane;
    const int rowL0 = chunk0 >> 3, c8L0 = chunk0 & 7;
    const int swc0 = (c8L0 ^ (rowL0 & 7)) << 3;
    const int chunk1 = chunk0 + 64;
    const int rowL1 = chunk1 >> 3, c8L1 = chunk1 & 7;
    const int swc1 = (c8L1 ^ (rowL1 & 7)) << 3;

    auto stageW = [&](const unsigned short* Wg, int buf) {   // buf 0..2
        __builtin_amdgcn_global_load_lds(
            (const __attribute__((address_space(1))) void*)(Wg + rowL0 * 64 + swc0),
            (__attribute__((address_space(3))) void*)(ldsb + 24576 + buf * 8192 + w * 2048),
            16, 0, 0);
        __builtin_amdgcn_global_load_lds(
            (const __attribute__((address_space(1))) void*)(Wg + rowL1 * 64 + swc1),
            (__attribute__((address_space(3))) void*)(ldsb + 24576 + buf * 8192 + w * 2048 + 1024),
            16, 0, 0);
    };
    auto stageA = [&](const unsigned short* Ag, int buf) {   // buf 0..2
        __builtin_amdgcn_global_load_lds(
            (const __attribute__((address_space(1))) void*)(Ag + rowL0 * 64 + swc0),
            (__attribute__((address_space(3))) void*)(ldsb + buf * 8192 + w * 2048),
            16, 0, 0);
        __builtin_amdgcn_global_load_lds(
            (const __attribute__((address_space(1))) void*)(Ag + rowL1 * 64 + swc1),
            (__attribute__((address_space(3))) void*)(ldsb + buf * 8192 + w * 2048 + 1024),
            16, 0, 0);
    };

    // ---- Phase A: out-projection over 8 heads (swapped: D[o2=bt*16+4g+r][p=w*16+c])
    f32x4 acc[4];
    #pragma unroll
    for (int bt = 0; bt < 4; ++bt) acc[bt] = (f32x4){0.f, 0.f, 0.f, 0.f};

    stageA(AO + (((size_t)bl * Hn + 0) * Pn + p0) * 64, 0);
    stageW(Weffl, 0);
    stageA(AO + (((size_t)bl * Hn + 1) * Pn + p0) * 64, 1);
    stageW(Weffl + 4096, 1);
    for (int h = 0; h < Hn; ++h) {
        const int cur = h % 3;
        if (h < 7) { VMCNT(4); } else { VMCNT(0); }
        __builtin_amdgcn_s_barrier();
        __builtin_amdgcn_sched_barrier(0);
        if (h < 6) {
            stageA(AO + (((size_t)bl * Hn + h + 2) * Pn + p0) * 64, (h + 2) % 3);
            stageW(Weffl + (size_t)(h + 2) * 4096, (h + 2) % 3);
        }
        __builtin_amdgcn_sched_barrier(0);
        char* Alb = ldsb + cur * 8192;
        char* Wlb = ldsb + 24576 + cur * 8192;
        const int rowa = w * 16 + c;
        bf16x8 a0 = *(const bf16x8*)(Alb + rowa * 128 + 16 * ((g    ) ^ (c & 7)));
        bf16x8 a1 = *(const bf16x8*)(Alb + rowa * 128 + 16 * ((g + 4) ^ (c & 7)));
        #pragma unroll
        for (int bt = 0; bt < 4; ++bt) {
            int rowb = bt * 16 + c;
            bf16x8 w0 = *(const bf16x8*)(Wlb + rowb * 128 + 16 * ((g    ) ^ (rowb & 7)));
            bf16x8 w1 = *(const bf16x8*)(Wlb + rowb * 128 + 16 * ((g + 4) ^ (rowb & 7)));
            acc[bt] = __builtin_amdgcn_mfma_f32_16x16x32_bf16(w0, a0, acc[bt], 0, 0, 0);
            acc[bt] = __builtin_amdgcn_mfma_f32_16x16x32_bf16(w1, a1, acc[bt], 0, 0, 0);
        }
    }

    const int p = w * 16 + c;
    if (last) {
        __syncthreads();
        #pragma unroll
        for (int bt = 0; bt < 4; ++bt) {
            f32x4 bb4 = *(const f32x4*)(bldc + bt * 16 + 4 * g);
            uint2 pk = {cvtpk(acc[bt][0] + bb4[0], acc[bt][1] + bb4[1]),
                        cvtpk(acc[bt][2] + bb4[2], acc[bt][3] + bb4[3])};
            *(uint2*)((char*)stg + p * 136 + (bt * 16 + 4 * g) * 2) = pk;
        }
        LGKM0();
        __syncthreads();
        #pragma unroll
        for (int i = 0; i < 4; ++i) {
            int chunk = tid + i * 256;
            int prow = chunk >> 4, c4 = chunk & 15;
            uint2 v = *(const uint2*)((const char*)stg + prow * 136 + c4 * 8);
            size_t grow = (size_t)(b_off + bl) * Pn + p0 + prow;
            *(uint2*)(xout + grow * 64 + c4 * 4) = v;
        }
        return;
    }

    // ---- Phase B: x-tile (bf16) into A buf0 (last read at h==6; all waves past h==7 top barrier)
    #pragma unroll
    for (int bt = 0; bt < 4; ++bt) {
        f32x4 bb4 = *(const f32x4*)(bldc + bt * 16 + 4 * g);
        uint2 pk = {cvtpk(acc[bt][0] + bb4[0], acc[bt][1] + bb4[1]),
                    cvtpk(acc[bt][2] + bb4[2], acc[bt][3] + bb4[3])};
        *(uint2*)(ldsb + p * 128 + ((2 * (bt * 16 + 4 * g)) ^ ((p & 7) << 4))) = pk;
    }
    stageW(Wqkv, 0);             // W buf0 last read at h==6 -> safe
    LGKM0();
    __builtin_amdgcn_s_barrier();       // all waves done h==7; x-tile visible
    __builtin_amdgcn_sched_barrier(0);
    stageW(Wqkv + 4096, 1);      // W buf1 last read at h==7; safe now

    const int rowa = w * 16 + c;
    bf16x8 a0 = *(const bf16x8*)(ldsb + rowa * 128 + 16 * ((g    ) ^ (c & 7)));
    bf16x8 a1 = *(const bf16x8*)(ldsb + rowa * 128 + 16 * ((g + 4) ^ (c & 7)));

    // ---- Phase C: next-layer QKV, 3-buffer 2-deep prefetch
    // VMCNT(6): need L(panel) (2 loads, issued at panel-2); younger ops at this point are
    // L(panel+1)x2 + S(panel-1)x4 = 6 -> waits exactly for L(panel) without draining stores.
    for (int panel = 0; panel < 24; ++panel) {
        const int mat = panel >> 3, h = panel & 7;
        const int cur = panel % 3;
        if (panel < 23) { VMCNT(6); } else { VMCNT(0); }
        __builtin_amdgcn_s_barrier();
        __builtin_amdgcn_sched_barrier(0);
        if (panel < 22) stageW(Wqkv + (size_t)(panel + 2) * 4096, (panel + 2) % 3);
        __builtin_amdgcn_sched_barrier(0);
        char* Wlb = ldsb + 24576 + cur * 8192;

        f32x4 pacc[4];
        #pragma unroll
        for (int bt = 0; bt < 4; ++bt) pacc[bt] = (f32x4){0.f, 0.f, 0.f, 0.f};
        const float* bbB = blds + mat * 512 + h * 64;

        if (mat < 2) {
            #pragma unroll
            for (int bt = 0; bt < 4; ++bt) {
                int rowb = bt * 16 + c;
                bf16x8 w0 = *(const bf16x8*)(Wlb + rowb * 128 + 16 * ((g    ) ^ (rowb & 7)));
                bf16x8 w1 = *(const bf16x8*)(Wlb + rowb * 128 + 16 * ((g + 4) ^ (rowb & 7)));
                pacc[bt] = __builtin_amdgcn_mfma_f32_16x16x32_bf16(w0, a0, pacc[bt], 0, 0, 0);
                pacc[bt] = __builtin_amdgcn_mfma_f32_16x16x32_bf16(w1, a1, pacc[bt], 0, 0, 0);
            }
            #pragma unroll
            for (int bt = 0; bt < 4; ++bt) {
                f32x4 bb4 = *(const f32x4*)(bbB + bt * 16 + 4 * g);
                float v0 = pacc[bt][0] + bb4[0];
                float v1 = pacc[bt][1] + bb4[1];
                float v2 = pacc[bt][2] + bb4[2];
                float v3 = pacc[bt][3] + bb4[3];
                if (mat == 0) { v0 *= C1F; v1 *= C1F; v2 *= C1F; v3 *= C1F; }
                if (bt == 3) {
                    float q49 = (mat == 0) ? -C2F : 1.0f;
                    bool g0 = (g == 0);
                    v0 = g0 ? v0 : 0.f;
                    v1 = g0 ? q49 : 0.f;
                    v2 = 0.f; v3 = 0.f;
                }
                uint2 pk = {cvtpk(v0, v1), cvtpk(v2, v3)};
                *(uint2*)((char*)stg + p * 136 + (bt * 16 + 4 * g) * 2) = pk;
            }
        } else {
            #pragma unroll
            for (int bt = 0; bt < 4; ++bt) {
                int rowb = bt * 16 + c;
                bf16x8 w0 = *(const bf16x8*)(Wlb + rowb * 128 + 16 * ((g    ) ^ (rowb & 7)));
                bf16x8 w1 = *(const bf16x8*)(Wlb + rowb * 128 + 16 * ((g + 4) ^ (rowb & 7)));
                pacc[bt] = __builtin_amdgcn_mfma_f32_16x16x32_bf16(a0, w0, pacc[bt], 0, 0, 0);
                pacc[bt] = __builtin_amdgcn_mfma_f32_16x16x32_bf16(a1, w1, pacc[bt], 0, 0, 0);
            }
            #pragma unroll
            for (int bt = 0; bt < 4; ++bt) {
                int d = bt * 16 + c;
                float bbd = bbB[d];
                float v0 = pacc[bt][0] + bbd;
                float v1 = pacc[bt][1] + bbd;
                float v2 = pacc[bt][2] + bbd;
                float v3 = pacc[bt][3] + bbd;
                if (bt == 3) {
                    bool is49 = (c == 1);
                    v0 = is49 ? 1.0f : v0;
                    v1 = is49 ? 1.0f : v1;
                    v2 = is49 ? 1.0f : v2;
                    v3 = is49 ? 1.0f : v3;
                }
                uint2 pk = {cvtpk(v0, v1), cvtpk(v2, v3)};
                *(uint2*)((char*)stg + d * 136 + (w * 16 + 4 * g) * 2) = pk;
            }
        }
        LGKM0();
        __builtin_amdgcn_s_barrier();

        if (mat < 2) {
            unsigned short* outp = (mat == 0) ? Qb : Kb;
            #pragma unroll
            for (int i = 0; i < 4; ++i) {
                int chunk = tid + i * 256;
                int prow = chunk >> 4, c4 = chunk & 15;
                uint2 v = *(const uint2*)((const char*)stg + prow * 136 + c4 * 8);
                int rr = r0 + prow;
                int bl2 = rr >> 9, pp = rr & 511;
                *(uint2*)(outp + (((size_t)bl2 * Hn + h) * Pn + pp) * 64 + c4 * 4) = v;
            }
        } else {
            #pragma unroll
            for (int i = 0; i < 4; ++i) {
                int chunk = tid + i * 256;
                int drow = chunk >> 4, c4 = chunk & 15;
                uint2 v = *(const uint2*)((const char*)stg + drow * 136 + c4 * 8);
                *(uint2*)(Vt + (((size_t)bl * Hn + h) * 64 + drow) * Pn + p0 + c4 * 4) = v;
            }
        }
    }
}

// ---------- mean-pool over P (bf16 input)
__global__ __launch_bounds__(256)
void pool_kernel(const unsigned short* __restrict__ x, float* __restrict__ pooled) {
    __shared__ float red[256];
    const int b = blockIdx.x;
    const int tid = threadIdx.x;
    const int ps = tid >> 6, d = tid & 63;
    float s = 0.f;
    for (int p = ps; p < Pn; p += 4) s += bf2f(x[((size_t)b * Pn + p) * 64 + d]);
    red[tid] = s;
    __syncthreads();
    if (tid < 64) {
        float t = red[tid] + red[tid + 64] + red[tid + 128] + red[tid + 192];
        if (tid < 49) pooled[b * 49 + tid] = t * (1.0f / Pn);
    }
}

// ---------- MLP + log-softmax + NLL
__global__ __launch_bounds__(64)
void head_kernel(const float* __restrict__ pooled, const int* __restrict__ labels,
                 const float* __restrict__ W1, const float* __restrict__ b1,
                 const float* __restrict__ W2, const float* __restrict__ b2,
                 float* __restrict__ out) {
    __shared__ float lloss[64];
    const int b = threadIdx.x;
    float pr[49];
    #pragma unroll
    for (int i = 0; i < 49; ++i) pr[i] = pooled[b * 49 + i];
    float hh[25];
    for (int j = 0; j < 25; ++j) {
        float s = b1[j];
        for (int i = 0; i < 49; ++i) s = fmaf(pr[i], W1[j * 49 + i], s);
        hh[j] = fmaxf(s, 0.f);
    }
    float lg[10];
    float m = -1e30f;
    for (int k = 0; k < 10; ++k) {
        float s = b2[k];
        for (int j = 0; j < 25; ++j) s = fmaf(hh[j], W2[k * 25 + j], s);
        lg[k] = s;
        m = fmaxf(m, s);
    }
    float se = 0.f;
    for (int k = 0; k < 10; ++k) se += __expf(lg[k] - m);
    float lse = m + __logf(se);
    int lbl = labels[b];
    lloss[b] = lse - lg[lbl];
    __syncthreads();
    if (b == 0) {
        float s = 0.f;
        for (int i = 0; i < 64; ++i) s += lloss[i];
        out[0] = s * (1.0f / 64.0f);
    }
}

extern "C" void kernel_launch(void* const* d_in, const int* in_sizes, int n_in,
                              void* d_out, int out_size, void* d_ws, size_t ws_size,
                              hipStream_t stream) {
    const float* emb    = (const float*)d_in[0];
    const int*   labels = (const int*)d_in[1];
    const float* Wq = (const float*)d_in[2];
    const float* bq = (const float*)d_in[3];
    const float* Wk = (const float*)d_in[4];
    const float* bk = (const float*)d_in[5];
    const float* Wv = (const float*)d_in[6];
    const float* bv = (const float*)d_in[7];
    const float* Wh = (const float*)d_in[8];
    const float* bhp = (const float*)d_in[9];
    const float* Wout = (const float*)d_in[10];
    const float* W1 = (const float*)d_in[11];
    const float* b1 = (const float*)d_in[12];
    const float* W2 = (const float*)d_in[13];
    const float* b2 = (const float*)d_in[14];
    float* out = (float*)d_out;

    char* base = (char*)d_ws;
    size_t off = 0;
    auto alloc = [&](size_t bytes) {
        off = (off + 255) & ~(size_t)255;
        char* p = base + off;
        off += bytes;
        return p;
    };

    unsigned short* WqkvB = (unsigned short*)alloc((size_t)Ln * 3 * Hn * 4096 * 2);
    unsigned short* WeffB = (unsigned short*)alloc((size_t)Ln * Hn * 4096 * 2);
    float*          beffB = (float*)alloc((size_t)Ln * 49 * 4);
    unsigned short* xA    = (unsigned short*)alloc((size_t)Bn * Pn * 64 * 2);
    unsigned short* xB    = (unsigned short*)alloc((size_t)Bn * Pn * 64 * 2);
    float*          pooled = (float*)alloc((size_t)Bn * 49 * 4);

    const size_t per_b = 4 * ((size_t)Hn * Pn * 64 * 2);   // Q + K + Vt + AO bf16
    size_t fixed = (off + 255) & ~(size_t)255;
    int Bc = Bn;
    while (Bc > 8 && fixed + (size_t)Bc * per_b + 4096 > ws_size) Bc >>= 1;

    unsigned short* Qb  = (unsigned short*)alloc((size_t)Bc * Hn * Pn * 64 * 2);
    unsigned short* Kb  = (unsigned short*)alloc((size_t)Bc * Hn * Pn * 64 * 2);
    unsigned short* Vtb = (unsigned short*)alloc((size_t)Bc * Hn * Pn * 64 * 2);
    unsigned short* AOb = (unsigned short*)alloc((size_t)Bc * Hn * Pn * 64 * 2);

    prep_wqkv_kernel<<<(Ln * 3 * Hn * 4096 + 255) / 256, 256, 0, stream>>>(Wq, Wk, Wv, WqkvB);
    prep_weff_kernel<<<(Ln * Hn * 4096 + Ln * 49 + 255) / 256, 256, 0, stream>>>(Wh, bhp, Wout, WeffB, beffB);
    cast_x_kernel<<<(Bn * Pn * 64) / 256, 256, 0, stream>>>(emb, xA);

    for (int b0 = 0; b0 < Bn; b0 += Bc) {
        qkv_mfma_kernel<<<Bc * 8, 256, 0, stream>>>(
            xA, WqkvB, bq, bk, bv, Qb, Kb, Vtb, b0, Bc);
        for (int l = 0; l < Ln; ++l) {
            attn_head_kernel<<<Bc * 16, 512, 0, stream>>>(Qb, Kb, Vtb, AOb, Bc);
            int last = (l == Ln - 1) ? 1 : 0;
            int ln = last ? 0 : (l + 1);
            outqkv_kernel<<<Bc * 8, 256, 0, stream>>>(
                AOb,
                WeffB + (size_t)l * Hn * 4096,
                beffB + (size_t)l * 49,
                WqkvB + (size_t)ln * 3 * Hn * 4096,
                bq + (size_t)ln * Hn * 49,
                bk + (size_t)ln * Hn * 49,
                bv + (size_t)ln * Hn * 49,
                Qb, Kb, Vtb, xB, last, b0, Bc);
        }
    }

    pool_kernel<<<Bn, 256, 0, stream>>>(xB, pooled);
    head_kernel<<<1, 64, 0, stream>>>(pooled, labels, W1, b1, W2, b2, out);
}

// Round 16
// 479.370 us; speedup vs baseline: 1.5877x; 1.0166x over previous
//
#include <hip/hip_runtime.h>
#include <hip/hip_bf16.h>
#include <math.h>

#define Bn 64
#define Pn 512
#define Hn 8
#define Ln 6

typedef __bf16 bf16x8 __attribute__((ext_vector_type(8)));
typedef float f32x4 __attribute__((ext_vector_type(4)));

#define VMCNT(n) asm volatile("s_waitcnt vmcnt(" #n ")" ::: "memory")
#define LGKM0()  asm volatile("s_waitcnt lgkmcnt(0)" ::: "memory")

static __device__ __forceinline__ unsigned short f2bf(float f) {
    return __builtin_bit_cast(unsigned short, __float2bfloat16(f));
}
static __device__ __forceinline__ float bf2f(unsigned short v) {
    unsigned int u = ((unsigned int)v) << 16;
    return __builtin_bit_cast(float, u);
}
static __device__ __forceinline__ float fexp2(float x) {
    float r;
    asm("v_exp_f32 %0, %1" : "=v"(r) : "v"(x));
    return r;
}
static __device__ __forceinline__ unsigned cvtpk(float a, float b) {
    unsigned r;
    asm("v_cvt_pk_bf16_f32 %0, %1, %2" : "=v"(r) : "v"(a), "v"(b));
    return r;
}

#define C1F (1.4426950408889634f / 7.000001f)   // log2(e)/SCALE
#define C2F 43.2808512f                         // 30*log2(e)

// ---------- prep: cast/pad Wq,Wk,Wv -> [L][3][H][64 o][64 i] bf16 (zero-padded)
__global__ __launch_bounds__(256)
void prep_wqkv_kernel(const float* __restrict__ Wq, const float* __restrict__ Wk,
                      const float* __restrict__ Wv, unsigned short* __restrict__ out) {
    int idx = blockIdx.x * 256 + threadIdx.x;
    if (idx >= Ln * 3 * Hn * 4096) return;
    int i = idx & 63, o = (idx >> 6) & 63, h = (idx >> 12) & 7, t = idx >> 15;
    int mat = t % 3, l = t / 3;
    float v = 0.f;
    if (o < 49 && i < 49) {
        const float* src = (mat == 0) ? Wq : (mat == 1) ? Wk : Wv;
        v = src[(((size_t)(l * Hn + h) * 49) + o) * 49 + i];
    }
    out[idx] = f2bf(v);
}

// ---------- prep: Weff[l][h][o2 64][o 64] bf16 = sum_dd Wh[l,h,dd,o]*Wout[l,o2,h*49+dd]
__global__ __launch_bounds__(256)
void prep_weff_kernel(const float* __restrict__ Wh, const float* __restrict__ bh,
                      const float* __restrict__ Wout,
                      unsigned short* __restrict__ Weff, float* __restrict__ beff) {
    const int NW = Ln * Hn * 4096;
    int idx = blockIdx.x * 256 + threadIdx.x;
    if (idx < NW) {
        int o = idx & 63, o2 = (idx >> 6) & 63, h = (idx >> 12) & 7, l = idx >> 15;
        float s = 0.f;
        if (o < 49 && o2 < 49) {
            const float* wh = Wh + ((size_t)(l * Hn + h) * 49) * 49 + o;   // [dd] stride 49
            const float* wo = Wout + ((size_t)l * 49 + o2) * 392 + h * 49; // [dd]
            for (int dd = 0; dd < 49; ++dd) s = fmaf(wh[dd * 49], wo[dd], s);
        }
        Weff[idx] = f2bf(s);
    } else if (idx < NW + Ln * 49) {
        int j = idx - NW;
        int l = j / 49, o2 = j % 49;
        const float* wo = Wout + ((size_t)l * 49 + o2) * 392;
        const float* bhl = bh + (size_t)l * 392;
        float s = 0.f;
        for (int cc = 0; cc < 392; ++cc) s = fmaf(bhl[cc], wo[cc], s);
        beff[j] = s;
    }
}

// ---------- prep: cast embedding -> x_bf [32768][64] padded
__global__ __launch_bounds__(256)
void cast_x_kernel(const float* __restrict__ emb, unsigned short* __restrict__ xbf) {
    int idx = blockIdx.x * 256 + threadIdx.x;
    int row = idx >> 6, col = idx & 63;
    float v = (col < 49) ? emb[(size_t)row * 49 + col] : 0.f;
    xbf[idx] = f2bf(v);
}

// ---------- QKV via MFMA (layer 0 only)
// Q pre-scaled by log2e/SCALE with Q[:,49] = -30*log2e; K[:,49] = 1; V^T[49][:] = 1.
__global__ __launch_bounds__(256)
void qkv_mfma_kernel(const unsigned short* __restrict__ xbf,
                     const unsigned short* __restrict__ Wqkv,
                     const float* __restrict__ bq_l, const float* __restrict__ bk_l,
                     const float* __restrict__ bv_l,
                     unsigned short* __restrict__ Qb, unsigned short* __restrict__ Kb,
                     unsigned short* __restrict__ Vt,
                     int b_off, int Bc) {
    __shared__ uint4 xlb4[512];
    __shared__ uint4 wlb4[512];
    __shared__ __align__(16) unsigned short stg[64 * 68];
    __shared__ __align__(16) float blds[1536];
    char* xlb = (char*)xlb4;
    char* wlb = (char*)wlb4;
    const int tid = threadIdx.x;
    const int w = tid >> 6, lane = tid & 63, g = lane >> 4, c = lane & 15;
    const int flat = blockIdx.x;
    const int bl = flat % Bc;
    const int tile = flat / Bc;
    const int r0 = bl * Pn + tile * 64;

    for (int t = tid; t < 1536; t += 256) {
        int mat = t >> 9, rem = t & 511, h = rem >> 6, o = rem & 63;
        const float* bb = (mat == 0) ? bq_l : (mat == 1) ? bk_l : bv_l;
        blds[t] = (o < 49) ? bb[h * 49 + o] : 0.f;
    }
    {
        const unsigned short* xg = xbf + ((size_t)b_off * Pn + r0) * 64;
        #pragma unroll
        for (int i = 0; i < 2; ++i) {
            int chunk = tid + i * 256;
            int row = chunk >> 3, c8 = chunk & 7;
            *(uint4*)(xlb + row * 128 + 16 * (c8 ^ (row & 7))) =
                *(const uint4*)(xg + row * 64 + c8 * 8);
        }
    }
    __syncthreads();

    const int rowa = w * 16 + c;
    bf16x8 a0 = *(const bf16x8*)(xlb + rowa * 128 + 16 * ((g    ) ^ (c & 7)));
    bf16x8 a1 = *(const bf16x8*)(xlb + rowa * 128 + 16 * ((g + 4) ^ (c & 7)));

    for (int panel = 0; panel < 24; ++panel) {
        const int mat = panel >> 3, h = panel & 7;
        const unsigned short* wg = Wqkv + (size_t)panel * 4096;
        #pragma unroll
        for (int i = 0; i < 2; ++i) {
            int chunk = tid + i * 256;
            int row = chunk >> 3, c8 = chunk & 7;
            *(uint4*)(wlb + row * 128 + 16 * (c8 ^ (row & 7))) =
                *(const uint4*)(wg + row * 64 + c8 * 8);
        }
        __syncthreads();

        f32x4 acc[4];
        #pragma unroll
        for (int bt = 0; bt < 4; ++bt) acc[bt] = (f32x4){0.f, 0.f, 0.f, 0.f};
        const float* bbB = blds + mat * 512 + h * 64;

        if (mat < 2) {
            // swapped: D[o=bt*16+4g+r][p=w*16+c] -> 4 consecutive o per lane
            #pragma unroll
            for (int bt = 0; bt < 4; ++bt) {
                int rowb = bt * 16 + c;
                bf16x8 w0 = *(const bf16x8*)(wlb + rowb * 128 + 16 * ((g    ) ^ (rowb & 7)));
                bf16x8 w1 = *(const bf16x8*)(wlb + rowb * 128 + 16 * ((g + 4) ^ (rowb & 7)));
                acc[bt] = __builtin_amdgcn_mfma_f32_16x16x32_bf16(w0, a0, acc[bt], 0, 0, 0);
                acc[bt] = __builtin_amdgcn_mfma_f32_16x16x32_bf16(w1, a1, acc[bt], 0, 0, 0);
            }
            const int p = w * 16 + c;
            #pragma unroll
            for (int bt = 0; bt < 4; ++bt) {
                f32x4 bb4 = *(const f32x4*)(bbB + bt * 16 + 4 * g);
                float v0 = acc[bt][0] + bb4[0];
                float v1 = acc[bt][1] + bb4[1];
                float v2 = acc[bt][2] + bb4[2];
                float v3 = acc[bt][3] + bb4[3];
                if (mat == 0) { v0 *= C1F; v1 *= C1F; v2 *= C1F; v3 *= C1F; }
                if (bt == 3) {
                    float q49 = (mat == 0) ? -C2F : 1.0f;
                    bool g0 = (g == 0);          // o = 48+4g+r
                    v0 = g0 ? v0 : 0.f;
                    v1 = g0 ? q49 : 0.f;
                    v2 = 0.f; v3 = 0.f;
                }
                uint2 pk = {cvtpk(v0, v1), cvtpk(v2, v3)};
                *(uint2*)((char*)stg + p * 136 + (bt * 16 + 4 * g) * 2) = pk;
            }
            LGKM0();
            __builtin_amdgcn_sched_barrier(0);
            // per-wave store: wave w owns stg rows w*16..w*16+15
            unsigned short* outp = (mat == 0) ? Qb : Kb;
            #pragma unroll
            for (int i = 0; i < 4; ++i) {
                int idx = i * 64 + lane;
                int prow = w * 16 + (idx >> 4), c4 = idx & 15;
                uint2 v = *(const uint2*)((const char*)stg + prow * 136 + c4 * 8);
                int rr = r0 + prow;
                int bl2 = rr >> 9, p2 = rr & 511;
                *(uint2*)(outp + (((size_t)bl2 * Hn + h) * Pn + p2) * 64 + c4 * 4) = v;
            }
            __syncthreads();   // protect wlb for next panel
        } else {
            // original: D[p=w*16+4g+r][o=bt*16+c] -> 4 consecutive p per lane (V^T)
            #pragma unroll
            for (int bt = 0; bt < 4; ++bt) {
                int rowb = bt * 16 + c;
                bf16x8 w0 = *(const bf16x8*)(wlb + rowb * 128 + 16 * ((g    ) ^ (rowb & 7)));
                bf16x8 w1 = *(const bf16x8*)(wlb + rowb * 128 + 16 * ((g + 4) ^ (rowb & 7)));
                acc[bt] = __builtin_amdgcn_mfma_f32_16x16x32_bf16(a0, w0, acc[bt], 0, 0, 0);
                acc[bt] = __builtin_amdgcn_mfma_f32_16x16x32_bf16(a1, w1, acc[bt], 0, 0, 0);
            }
            #pragma unroll
            for (int bt = 0; bt < 4; ++bt) {
                int d = bt * 16 + c;
                float bbd = bbB[d];
                float v0 = acc[bt][0] + bbd;
                float v1 = acc[bt][1] + bbd;
                float v2 = acc[bt][2] + bbd;
                float v3 = acc[bt][3] + bbd;
                if (bt == 3) {
                    bool is49 = (c == 1);        // d = 48+c
                    v0 = is49 ? 1.0f : v0;
                    v1 = is49 ? 1.0f : v1;
                    v2 = is49 ? 1.0f : v2;
                    v3 = is49 ? 1.0f : v3;
                }
                uint2 pk = {cvtpk(v0, v1), cvtpk(v2, v3)};
                *(uint2*)((char*)stg + d * 136 + (w * 16 + 4 * g) * 2) = pk;
            }
            __syncthreads();
            const int bl2 = r0 >> 9, p0 = r0 & 511;
            #pragma unroll
            for (int i = 0; i < 4; ++i) {
                int chunk = tid + i * 256;
                int drow = chunk >> 4, c4 = chunk & 15;
                uint2 v = *(const uint2*)((const char*)stg + drow * 136 + c4 * 8);
                *(uint2*)(Vt + (((size_t)bl2 * Hn + h) * 64 + drow) * Pn + p0 + c4 * 4) = v;
            }
            __syncthreads();
        }
    }
}

// ---------- per-head attention: 8 waves x 256 q-rows; async dbuf; in-register P; ones-row denom
__global__ __launch_bounds__(512, 2)
void attn_head_kernel(const unsigned short* __restrict__ Qb,
                      const unsigned short* __restrict__ Kb,
                      const unsigned short* __restrict__ Vt,
                      unsigned short* __restrict__ AO,   // [Bc][H][P][64] bf16
                      int Bc) {
    // 32 KiB: K dbuf 2x8K | V dbuf 2x8K  (epilogue staging reuses whole area)
    __shared__ uint4 lds4[2048];
    char* ldsb = (char*)lds4;
    const int tid = threadIdx.x;
    const int w = tid >> 6, lane = tid & 63, g = lane >> 4, c = lane & 15;
    const int flat = blockIdx.x;
    const int x = flat & 7;
    const int qt = (flat >> 3) & 1;
    const int a = flat >> 4;
    const size_t bh = (size_t)(a * 8 + x);
    const int q0 = qt * 256;

    bf16x8 qf[2][2];
    #pragma unroll
    for (int qs = 0; qs < 2; ++qs) {
        const unsigned short* qp = Qb + (bh * Pn + q0 + w * 32 + qs * 16 + c) * 64;
        qf[qs][0] = *(const bf16x8*)(qp + g * 8);
        qf[qs][1] = *(const bf16x8*)(qp + g * 8 + 32);
    }
    f32x4 oacc[2][4];
    #pragma unroll
    for (int qs = 0; qs < 2; ++qs)
        #pragma unroll
        for (int dt = 0; dt < 4; ++dt)
            oacc[qs][dt] = (f32x4){0.f, 0.f, 0.f, 0.f};

    const unsigned short* Kg0 = Kb + bh * (size_t)(Pn * 64);
    const unsigned short* Vg0 = Vt + bh * (size_t)(64 * Pn);

    const int rowS = tid >> 3, c8S = tid & 7;
    const int swcS = (c8S ^ (rowS & 7)) << 3;
    auto stage = [&](int kt, int buf) {
        const unsigned short* Kg = Kg0 + kt * (64 * 64);
        const unsigned short* Vg = Vg0 + kt * 64;
        __builtin_amdgcn_global_load_lds(
            (const __attribute__((address_space(1))) void*)(Kg + rowS * 64 + swcS),
            (__attribute__((address_space(3))) void*)(ldsb + buf * 8192 + w * 1024),
            16, 0, 0);
        __builtin_amdgcn_global_load_lds(
            (const __attribute__((address_space(1))) void*)(Vg + (size_t)rowS * Pn + swcS),
            (__attribute__((address_space(3))) void*)(ldsb + 16384 + buf * 8192 + w * 1024),
            16, 0, 0);
    };

    stage(0, 0);

    #pragma unroll 2
    for (int kt = 0; kt < 8; ++kt) {
        const int cur = kt & 1;
        VMCNT(0);
        __builtin_amdgcn_s_barrier();
        __builtin_amdgcn_sched_barrier(0);
        if (kt < 7) stage(kt + 1, cur ^ 1);
        __builtin_amdgcn_sched_barrier(0);

        char* Klb = ldsb + cur * 8192;
        char* Vlb = ldsb + 16384 + cur * 8192;

        unsigned up01[2][4], up23[2][4];
        #pragma unroll
        for (int t = 0; t < 4; ++t) {
            const int krow = t * 16 + c;
            bf16x8 kf0 = *(const bf16x8*)(Klb + krow * 128 + 16 * ((g    ) ^ (krow & 7)));
            bf16x8 kf1 = *(const bf16x8*)(Klb + krow * 128 + 16 * ((g + 4) ^ (krow & 7)));
            #pragma unroll
            for (int qs = 0; qs < 2; ++qs) {
                f32x4 s4 = {0.f, 0.f, 0.f, 0.f};
                __builtin_amdgcn_s_setprio(1);
                s4 = __builtin_amdgcn_mfma_f32_16x16x32_bf16(kf0, qf[qs][0], s4, 0, 0, 0);
                s4 = __builtin_amdgcn_mfma_f32_16x16x32_bf16(kf1, qf[qs][1], s4, 0, 0, 0);
                __builtin_amdgcn_s_setprio(0);
                float p0 = fexp2(s4[0]);
                float p1 = fexp2(s4[1]);
                float p2 = fexp2(s4[2]);
                float p3 = fexp2(s4[3]);
                up01[qs][t] = cvtpk(p0, p1);
                up23[qs][t] = cvtpk(p2, p3);
            }
        }

        #pragma unroll
        for (int kk = 0; kk < 2; ++kk) {
            bf16x8 pa[2];
            #pragma unroll
            for (int qs = 0; qs < 2; ++qs) {
                unsigned d0 = up01[qs][2 * kk], d2 = up01[qs][2 * kk + 1];
                unsigned d1 = up23[qs][2 * kk], d3 = up23[qs][2 * kk + 1];
                asm("v_permlane32_swap_b32 %0, %1" : "+v"(d0), "+v"(d2));
                asm("v_permlane16_swap_b32 %0, %1" : "+v"(d0), "+v"(d2));
                asm("v_permlane32_swap_b32 %0, %1" : "+v"(d1), "+v"(d3));
                asm("v_permlane16_swap_b32 %0, %1" : "+v"(d1), "+v"(d3));
                uint4 uv = {d0, d1, d2, d3};
                pa[qs] = __builtin_bit_cast(bf16x8, uv);
            }
            __builtin_amdgcn_s_setprio(1);
            #pragma unroll
            for (int dt = 0; dt < 4; ++dt) {
                const int vrow = dt * 16 + c;
                bf16x8 vf = *(const bf16x8*)(Vlb + vrow * 128 + 16 * ((g + 4 * kk) ^ (vrow & 7)));
                oacc[0][dt] = __builtin_amdgcn_mfma_f32_16x16x32_bf16(pa[0], vf, oacc[0][dt], 0, 0, 0);
                oacc[1][dt] = __builtin_amdgcn_mfma_f32_16x16x32_bf16(pa[1], vf, oacc[1][dt], 0, 0, 0);
            }
            __builtin_amdgcn_s_setprio(0);
        }
    }
    __builtin_amdgcn_s_barrier();

    float rinv[2][4];
    #pragma unroll
    for (int qs = 0; qs < 2; ++qs)
        #pragma unroll
        for (int r = 0; r < 4; ++r) {
            float s = __shfl(oacc[qs][3][r], (lane & 48) | 1);
            rinv[qs][r] = 1.0f / s;
        }
    char* stgw = ldsb + w * 4096;
    #pragma unroll
    for (int qs = 0; qs < 2; ++qs)
        #pragma unroll
        for (int dt = 0; dt < 4; ++dt)
            #pragma unroll
            for (int r = 0; r < 4; ++r) {
                int prow = qs * 16 + 4 * g + r;
                int col = dt * 16 + c;
                *(unsigned short*)(stgw + prow * 128 + ((2 * col) ^ ((prow & 7) << 4))) =
                    f2bf(oacc[qs][dt][r] * rinv[qs][r]);
            }
    LGKM0();
    __builtin_amdgcn_sched_barrier(0);
    #pragma unroll
    for (int i = 0; i < 4; ++i) {
        int chunk = i * 64 + lane;
        int row = chunk >> 3, c8 = chunk & 7;
        uint4 v = *(const uint4*)(stgw + row * 128 + 16 * (c8 ^ (row & 7)));
        size_t grow = bh * Pn + q0 + w * 32 + row;
        *(uint4*)(AO + grow * 64 + c8 * 8) = v;
    }
}

// ---------- fused out-projection + next-layer QKV; 3-buffer 2-deep prefetch
__global__ __launch_bounds__(256)
void outqkv_kernel(const unsigned short* __restrict__ AO,     // [Bc][H][P][64]
                   const unsigned short* __restrict__ Weffl,  // [8][64][64]
                   const float* __restrict__ beffl,           // [49]
                   const unsigned short* __restrict__ Wqkv,   // next layer [3][8][64][64]
                   const float* __restrict__ bq_l, const float* __restrict__ bk_l,
                   const float* __restrict__ bv_l,
                   unsigned short* __restrict__ Qb, unsigned short* __restrict__ Kb,
                   unsigned short* __restrict__ Vt,
                   unsigned short* __restrict__ xout,         // used only when last
                   int last, int b_off, int Bc) {
    // A bufs: 0 / 8192 / 16384 | W bufs: 24576 / 32768 / 40960 | stg @ 49152 (8704)
    __shared__ uint4 lds4[3616];
    __shared__ __align__(16) float blds[1536];
    __shared__ __align__(16) float bldc[64];
    char* ldsb = (char*)lds4;
    unsigned short* stg = (unsigned short*)(ldsb + 49152);
    const int tid = threadIdx.x;
    const int w = tid >> 6, lane = tid & 63, g = lane >> 4, c = lane & 15;
    const int flat = blockIdx.x;
    const int bl = flat % Bc;
    const int tile = flat / Bc;
    const int p0 = tile * 64;
    const int r0 = bl * Pn + p0;

    if (!last) {
        for (int t = tid; t < 1536; t += 256) {
            int mat = t >> 9, rem = t & 511, h = rem >> 6, o = rem & 63;
            const float* bb = (mat == 0) ? bq_l : (mat == 1) ? bk_l : bv_l;
            blds[t] = (o < 49) ? bb[h * 49 + o] : 0.f;
        }
    }
    if (tid < 64) bldc[tid] = (tid < 49) ? beffl[tid] : 0.f;

    const int chunk0 = w * 128 + lane;
    const int rowL0 = chunk0 >> 3, c8L0 = chunk0 & 7;
    const int swc0 = (c8L0 ^ (rowL0 & 7)) << 3;
    const int chunk1 = chunk0 + 64;
    const int rowL1 = chunk1 >> 3, c8L1 = chunk1 & 7;
    const int swc1 = (c8L1 ^ (rowL1 & 7)) << 3;

    auto stageW = [&](const unsigned short* Wg, int buf) {   // buf 0..2
        __builtin_amdgcn_global_load_lds(
            (const __attribute__((address_space(1))) void*)(Wg + rowL0 * 64 + swc0),
            (__attribute__((address_space(3))) void*)(ldsb + 24576 + buf * 8192 + w * 2048),
            16, 0, 0);
        __builtin_amdgcn_global_load_lds(
            (const __attribute__((address_space(1))) void*)(Wg + rowL1 * 64 + swc1),
            (__attribute__((address_space(3))) void*)(ldsb + 24576 + buf * 8192 + w * 2048 + 1024),
            16, 0, 0);
    };
    auto stageA = [&](const unsigned short* Ag, int buf) {   // buf 0..2
        __builtin_amdgcn_global_load_lds(
            (const __attribute__((address_space(1))) void*)(Ag + rowL0 * 64 + swc0),
            (__attribute__((address_space(3))) void*)(ldsb + buf * 8192 + w * 2048),
            16, 0, 0);
        __builtin_amdgcn_global_load_lds(
            (const __attribute__((address_space(1))) void*)(Ag + rowL1 * 64 + swc1),
            (__attribute__((address_space(3))) void*)(ldsb + buf * 8192 + w * 2048 + 1024),
            16, 0, 0);
    };

    // ---- Phase A: out-projection over 8 heads (swapped: D[o2=bt*16+4g+r][p=w*16+c])
    f32x4 acc[4];
    #pragma unroll
    for (int bt = 0; bt < 4; ++bt) acc[bt] = (f32x4){0.f, 0.f, 0.f, 0.f};

    stageA(AO + (((size_t)bl * Hn + 0) * Pn + p0) * 64, 0);
    stageW(Weffl, 0);
    stageA(AO + (((size_t)bl * Hn + 1) * Pn + p0) * 64, 1);
    stageW(Weffl + 4096, 1);
    for (int h = 0; h < Hn; ++h) {
        const int cur = h % 3;
        if (h < 7) { VMCNT(4); } else { VMCNT(0); }
        __builtin_amdgcn_s_barrier();
        __builtin_amdgcn_sched_barrier(0);
        if (h < 6) {
            stageA(AO + (((size_t)bl * Hn + h + 2) * Pn + p0) * 64, (h + 2) % 3);
            stageW(Weffl + (size_t)(h + 2) * 4096, (h + 2) % 3);
        }
        __builtin_amdgcn_sched_barrier(0);
        char* Alb = ldsb + cur * 8192;
        char* Wlb = ldsb + 24576 + cur * 8192;
        const int rowa = w * 16 + c;
        bf16x8 a0 = *(const bf16x8*)(Alb + rowa * 128 + 16 * ((g    ) ^ (c & 7)));
        bf16x8 a1 = *(const bf16x8*)(Alb + rowa * 128 + 16 * ((g + 4) ^ (c & 7)));
        #pragma unroll
        for (int bt = 0; bt < 4; ++bt) {
            int rowb = bt * 16 + c;
            bf16x8 w0 = *(const bf16x8*)(Wlb + rowb * 128 + 16 * ((g    ) ^ (rowb & 7)));
            bf16x8 w1 = *(const bf16x8*)(Wlb + rowb * 128 + 16 * ((g + 4) ^ (rowb & 7)));
            acc[bt] = __builtin_amdgcn_mfma_f32_16x16x32_bf16(w0, a0, acc[bt], 0, 0, 0);
            acc[bt] = __builtin_amdgcn_mfma_f32_16x16x32_bf16(w1, a1, acc[bt], 0, 0, 0);
        }
    }

    const int p = w * 16 + c;
    if (last) {
        __syncthreads();
        #pragma unroll
        for (int bt = 0; bt < 4; ++bt) {
            f32x4 bb4 = *(const f32x4*)(bldc + bt * 16 + 4 * g);
            uint2 pk = {cvtpk(acc[bt][0] + bb4[0], acc[bt][1] + bb4[1]),
                        cvtpk(acc[bt][2] + bb4[2], acc[bt][3] + bb4[3])};
            *(uint2*)((char*)stg + p * 136 + (bt * 16 + 4 * g) * 2) = pk;
        }
        LGKM0();
        __builtin_amdgcn_sched_barrier(0);
        #pragma unroll
        for (int i = 0; i < 4; ++i) {
            int idx = i * 64 + lane;
            int prow = w * 16 + (idx >> 4), c4 = idx & 15;
            uint2 v = *(const uint2*)((const char*)stg + prow * 136 + c4 * 8);
            size_t grow = (size_t)(b_off + bl) * Pn + p0 + prow;
            *(uint2*)(xout + grow * 64 + c4 * 4) = v;
        }
        return;
    }

    // ---- Phase B: x-tile (bf16) into A buf0 (last read at h==6; all waves past h==7 top barrier)
    #pragma unroll
    for (int bt = 0; bt < 4; ++bt) {
        f32x4 bb4 = *(const f32x4*)(bldc + bt * 16 + 4 * g);
        uint2 pk = {cvtpk(acc[bt][0] + bb4[0], acc[bt][1] + bb4[1]),
                    cvtpk(acc[bt][2] + bb4[2], acc[bt][3] + bb4[3])};
        *(uint2*)(ldsb + p * 128 + ((2 * (bt * 16 + 4 * g)) ^ ((p & 7) << 4))) = pk;
    }
    stageW(Wqkv, 0);             // W buf0 last read at h==6 -> safe
    LGKM0();
    __builtin_amdgcn_s_barrier();       // all waves done h==7; x-tile visible
    __builtin_amdgcn_sched_barrier(0);
    stageW(Wqkv + 4096, 1);      // W buf1 last read at h==7; safe now

    const int rowa = w * 16 + c;
    bf16x8 a0 = *(const bf16x8*)(ldsb + rowa * 128 + 16 * ((g    ) ^ (c & 7)));
    bf16x8 a1 = *(const bf16x8*)(ldsb + rowa * 128 + 16 * ((g + 4) ^ (c & 7)));

    // ---- Phase C: next-layer QKV, 3-buffer 2-deep prefetch
    // VMCNT(6): retires L(panel) without draining stores (see round-14 derivation).
    for (int panel = 0; panel < 24; ++panel) {
        const int mat = panel >> 3, h = panel & 7;
        const int cur = panel % 3;
        if (panel < 23) { VMCNT(6); } else { VMCNT(0); }
        __builtin_amdgcn_s_barrier();
        __builtin_amdgcn_sched_barrier(0);
        if (panel < 22) stageW(Wqkv + (size_t)(panel + 2) * 4096, (panel + 2) % 3);
        __builtin_amdgcn_sched_barrier(0);
        char* Wlb = ldsb + 24576 + cur * 8192;

        f32x4 pacc[4];
        #pragma unroll
        for (int bt = 0; bt < 4; ++bt) pacc[bt] = (f32x4){0.f, 0.f, 0.f, 0.f};
        const float* bbB = blds + mat * 512 + h * 64;

        if (mat < 2) {
            #pragma unroll
            for (int bt = 0; bt < 4; ++bt) {
                int rowb = bt * 16 + c;
                bf16x8 w0 = *(const bf16x8*)(Wlb + rowb * 128 + 16 * ((g    ) ^ (rowb & 7)));
                bf16x8 w1 = *(const bf16x8*)(Wlb + rowb * 128 + 16 * ((g + 4) ^ (rowb & 7)));
                pacc[bt] = __builtin_amdgcn_mfma_f32_16x16x32_bf16(w0, a0, pacc[bt], 0, 0, 0);
                pacc[bt] = __builtin_amdgcn_mfma_f32_16x16x32_bf16(w1, a1, pacc[bt], 0, 0, 0);
            }
            #pragma unroll
            for (int bt = 0; bt < 4; ++bt) {
                f32x4 bb4 = *(const f32x4*)(bbB + bt * 16 + 4 * g);
                float v0 = pacc[bt][0] + bb4[0];
                float v1 = pacc[bt][1] + bb4[1];
                float v2 = pacc[bt][2] + bb4[2];
                float v3 = pacc[bt][3] + bb4[3];
                if (mat == 0) { v0 *= C1F; v1 *= C1F; v2 *= C1F; v3 *= C1F; }
                if (bt == 3) {
                    float q49 = (mat == 0) ? -C2F : 1.0f;
                    bool g0 = (g == 0);
                    v0 = g0 ? v0 : 0.f;
                    v1 = g0 ? q49 : 0.f;
                    v2 = 0.f; v3 = 0.f;
                }
                uint2 pk = {cvtpk(v0, v1), cvtpk(v2, v3)};
                *(uint2*)((char*)stg + p * 136 + (bt * 16 + 4 * g) * 2) = pk;
            }
            // per-wave epilogue: wave w owns stg rows w*16..w*16+15 -> no block barrier
            LGKM0();
            __builtin_amdgcn_sched_barrier(0);
            unsigned short* outp = (mat == 0) ? Qb : Kb;
            #pragma unroll
            for (int i = 0; i < 4; ++i) {
                int idx = i * 64 + lane;
                int prow = w * 16 + (idx >> 4), c4 = idx & 15;
                uint2 v = *(const uint2*)((const char*)stg + prow * 136 + c4 * 8);
                int rr = r0 + prow;
                int bl2 = rr >> 9, pp = rr & 511;
                *(uint2*)(outp + (((size_t)bl2 * Hn + h) * Pn + pp) * 64 + c4 * 4) = v;
            }
        } else {
            #pragma unroll
            for (int bt = 0; bt < 4; ++bt) {
                int rowb = bt * 16 + c;
                bf16x8 w0 = *(const bf16x8*)(Wlb + rowb * 128 + 16 * ((g    ) ^ (rowb & 7)));
                bf16x8 w1 = *(const bf16x8*)(Wlb + rowb * 128 + 16 * ((g + 4) ^ (rowb & 7)));
                pacc[bt] = __builtin_amdgcn_mfma_f32_16x16x32_bf16(a0, w0, pacc[bt], 0, 0, 0);
                pacc[bt] = __builtin_amdgcn_mfma_f32_16x16x32_bf16(a1, w1, pacc[bt], 0, 0, 0);
            }
            #pragma unroll
            for (int bt = 0; bt < 4; ++bt) {
                int d = bt * 16 + c;
                float bbd = bbB[d];
                float v0 = pacc[bt][0] + bbd;
                float v1 = pacc[bt][1] + bbd;
                float v2 = pacc[bt][2] + bbd;
                float v3 = pacc[bt][3] + bbd;
                if (bt == 3) {
                    bool is49 = (c == 1);
                    v0 = is49 ? 1.0f : v0;
                    v1 = is49 ? 1.0f : v1;
                    v2 = is49 ? 1.0f : v2;
                    v3 = is49 ? 1.0f : v3;
                }
                uint2 pk = {cvtpk(v0, v1), cvtpk(v2, v3)};
                *(uint2*)((char*)stg + d * 136 + (w * 16 + 4 * g) * 2) = pk;
            }
            LGKM0();
            __builtin_amdgcn_s_barrier();   // V^T re-tile is cross-wave
            #pragma unroll
            for (int i = 0; i < 4; ++i) {
                int chunk = tid + i * 256;
                int drow = chunk >> 4, c4 = chunk & 15;
                uint2 v = *(const uint2*)((const char*)stg + drow * 136 + c4 * 8);
                *(uint2*)(Vt + (((size_t)bl * Hn + h) * 64 + drow) * Pn + p0 + c4 * 4) = v;
            }
        }
    }
}

// ---------- mean-pool over P (bf16 input)
__global__ __launch_bounds__(256)
void pool_kernel(const unsigned short* __restrict__ x, float* __restrict__ pooled) {
    __shared__ float red[256];
    const int b = blockIdx.x;
    const int tid = threadIdx.x;
    const int ps = tid >> 6, d = tid & 63;
    float s = 0.f;
    for (int p = ps; p < Pn; p += 4) s += bf2f(x[((size_t)b * Pn + p) * 64 + d]);
    red[tid] = s;
    __syncthreads();
    if (tid < 64) {
        float t = red[tid] + red[tid + 64] + red[tid + 128] + red[tid + 192];
        if (tid < 49) pooled[b * 49 + tid] = t * (1.0f / Pn);
    }
}

// ---------- MLP + log-softmax + NLL
__global__ __launch_bounds__(64)
void head_kernel(const float* __restrict__ pooled, const int* __restrict__ labels,
                 const float* __restrict__ W1, const float* __restrict__ b1,
                 const float* __restrict__ W2, const float* __restrict__ b2,
                 float* __restrict__ out) {
    __shared__ float lloss[64];
    const int b = threadIdx.x;
    float pr[49];
    #pragma unroll
    for (int i = 0; i < 49; ++i) pr[i] = pooled[b * 49 + i];
    float hh[25];
    for (int j = 0; j < 25; ++j) {
        float s = b1[j];
        for (int i = 0; i < 49; ++i) s = fmaf(pr[i], W1[j * 49 + i], s);
        hh[j] = fmaxf(s, 0.f);
    }
    float lg[10];
    float m = -1e30f;
    for (int k = 0; k < 10; ++k) {
        float s = b2[k];
        for (int j = 0; j < 25; ++j) s = fmaf(hh[j], W2[k * 25 + j], s);
        lg[k] = s;
        m = fmaxf(m, s);
    }
    float se = 0.f;
    for (int k = 0; k < 10; ++k) se += __expf(lg[k] - m);
    float lse = m + __logf(se);
    int lbl = labels[b];
    lloss[b] = lse - lg[lbl];
    __syncthreads();
    if (b == 0) {
        float s = 0.f;
        for (int i = 0; i < 64; ++i) s += lloss[i];
        out[0] = s * (1.0f / 64.0f);
    }
}

extern "C" void kernel_launch(void* const* d_in, const int* in_sizes, int n_in,
                              void* d_out, int out_size, void* d_ws, size_t ws_size,
                              hipStream_t stream) {
    const float* emb    = (const float*)d_in[0];
    const int*   labels = (const int*)d_in[1];
    const float* Wq = (const float*)d_in[2];
    const float* bq = (const float*)d_in[3];
    const float* Wk = (const float*)d_in[4];
    const float* bk = (const float*)d_in[5];
    const float* Wv = (const float*)d_in[6];
    const float* bv = (const float*)d_in[7];
    const float* Wh = (const float*)d_in[8];
    const float* bhp = (const float*)d_in[9];
    const float* Wout = (const float*)d_in[10];
    const float* W1 = (const float*)d_in[11];
    const float* b1 = (const float*)d_in[12];
    const float* W2 = (const float*)d_in[13];
    const float* b2 = (const float*)d_in[14];
    float* out = (float*)d_out;

    char* base = (char*)d_ws;
    size_t off = 0;
    auto alloc = [&](size_t bytes) {
        off = (off + 255) & ~(size_t)255;
        char* p = base + off;
        off += bytes;
        return p;
    };

    unsigned short* WqkvB = (unsigned short*)alloc((size_t)Ln * 3 * Hn * 4096 * 2);
    unsigned short* WeffB = (unsigned short*)alloc((size_t)Ln * Hn * 4096 * 2);
    float*          beffB = (float*)alloc((size_t)Ln * 49 * 4);
    unsigned short* xA    = (unsigned short*)alloc((size_t)Bn * Pn * 64 * 2);
    unsigned short* xB    = (unsigned short*)alloc((size_t)Bn * Pn * 64 * 2);
    float*          pooled = (float*)alloc((size_t)Bn * 49 * 4);

    const size_t per_b = 4 * ((size_t)Hn * Pn * 64 * 2);   // Q + K + Vt + AO bf16
    size_t fixed = (off + 255) & ~(size_t)255;
    int Bc = Bn;
    while (Bc > 8 && fixed + (size_t)Bc * per_b + 4096 > ws_size) Bc >>= 1;

    unsigned short* Qb  = (unsigned short*)alloc((size_t)Bc * Hn * Pn * 64 * 2);
    unsigned short* Kb  = (unsigned short*)alloc((size_t)Bc * Hn * Pn * 64 * 2);
    unsigned short* Vtb = (unsigned short*)alloc((size_t)Bc * Hn * Pn * 64 * 2);
    unsigned short* AOb = (unsigned short*)alloc((size_t)Bc * Hn * Pn * 64 * 2);

    prep_wqkv_kernel<<<(Ln * 3 * Hn * 4096 + 255) / 256, 256, 0, stream>>>(Wq, Wk, Wv, WqkvB);
    prep_weff_kernel<<<(Ln * Hn * 4096 + Ln * 49 + 255) / 256, 256, 0, stream>>>(Wh, bhp, Wout, WeffB, beffB);
    cast_x_kernel<<<(Bn * Pn * 64) / 256, 256, 0, stream>>>(emb, xA);

    for (int b0 = 0; b0 < Bn; b0 += Bc) {
        qkv_mfma_kernel<<<Bc * 8, 256, 0, stream>>>(
            xA, WqkvB, bq, bk, bv, Qb, Kb, Vtb, b0, Bc);
        for (int l = 0; l < Ln; ++l) {
            attn_head_kernel<<<Bc * 16, 512, 0, stream>>>(Qb, Kb, Vtb, AOb, Bc);
            int last = (l == Ln - 1) ? 1 : 0;
            int ln = last ? 0 : (l + 1);
            outqkv_kernel<<<Bc * 8, 256, 0, stream>>>(
                AOb,
                WeffB + (size_t)l * Hn * 4096,
                beffB + (size_t)l * 49,
                WqkvB + (size_t)ln * 3 * Hn * 4096,
                bq + (size_t)ln * Hn * 49,
                bk + (size_t)ln * Hn * 49,
                bv + (size_t)ln * Hn * 49,
                Qb, Kb, Vtb, xB, last, b0, Bc);
        }
    }

    pool_kernel<<<Bn, 256, 0, stream>>>(xB, pooled);
    head_kernel<<<1, 64, 0, stream>>>(pooled, labels, W1, b1, W2, b2, out);
}